// Round 12
// baseline (310.897 us; speedup 1.0000x reference)
//
#include <hip/hip_runtime.h>
#include <hip/hip_bf16.h>

// Problem constants
#define HWSZ   262144   // 512*512
#define IMG    512
#define NBATCH 4
#define NBANDS 8

typedef _Float16 half_t;
typedef _Float16 half2v __attribute__((ext_vector_type(2)));
typedef _Float16 half4v __attribute__((ext_vector_type(4)));
typedef _Float16 half8v __attribute__((ext_vector_type(8)));

// ---------------------------------------------------------------------------
// Block-level reduction: wave shuffle + LDS + one double atomic per block.
__device__ __forceinline__ void blockReduceAtomicAdd(double v, double* target,
                                                     double* red) {
    for (int off = 32; off > 0; off >>= 1) v += __shfl_down(v, off, 64);
    const int wave = threadIdx.x >> 6, lane = threadIdx.x & 63;
    if (lane == 0) red[wave] = v;
    __syncthreads();
    if (threadIdx.x == 0) atomicAdd(target, red[0] + red[1] + red[2] + red[3]);
}

// ---------------------------------------------------------------------------
// Pan smoothing (edge-pad 41x41 Gaussian, rank-1 factored), horizontal pass.
__global__ __launch_bounds__(256) void k_pan_h(const float* __restrict__ inp,
                                               const float* __restrict__ mtf,
                                               float* __restrict__ tmpH) {
    __shared__ float seg[296];
    __shared__ float vrow[41];
    const int tid = threadIdx.x;
    const int b = blockIdx.z, r = blockIdx.y, c0 = blockIdx.x * 256;
    if (tid < 41) vrow[tid] = mtf[20 * 41 + tid] / sqrtf(mtf[20 * 41 + 20]);
    const float* pan = inp + ((long)b * 9 + 8) * HWSZ + (long)r * IMG;
    for (int e = tid; e < 296; e += 256) {
        int c = c0 - 20 + e;
        c = min(max(c, 0), IMG - 1);
        seg[e] = pan[c];
    }
    __syncthreads();
    float s = 0.f;
#pragma unroll
    for (int j = 0; j < 41; ++j) s += vrow[j] * seg[tid + j];
    tmpH[(long)b * HWSZ + (long)r * IMG + c0 + tid] = s;
}

__global__ __launch_bounds__(256) void k_pan_v(const float* __restrict__ tmpH,
                                               const float* __restrict__ mtf,
                                               float* __restrict__ panf) {
    __shared__ float ucol[41];
    const int tid = threadIdx.x;
    const int b = blockIdx.z, r = blockIdx.y, c = blockIdx.x * 256 + tid;
    if (tid < 41) ucol[tid] = mtf[tid * 41 + 20] / sqrtf(mtf[20 * 41 + 20]);
    __syncthreads();
    const float* base = tmpH + (long)b * HWSZ;
    float s = 0.f;
#pragma unroll
    for (int i = 0; i < 41; ++i) {
        int rr = min(max(r - 20 + i, 0), IMG - 1);
        s += ucol[i] * base[(long)rr * IMG + c];
    }
    panf[(long)b * HWSZ + (long)r * IMG + c] = s;
}

// ---------------------------------------------------------------------------
// Small-field (4-image) helpers, LDS tile based (cheap at this size).
template <int W>
__global__ __launch_bounds__(256) void k_da(const float* __restrict__ in,
                                            long inBatchStride,
                                            float* __restrict__ out) {
    constexpr int TS = 32, WIN = 2 * W, NN = 4 * W * W, RE = TS + WIN - 1;
    constexpr int SR = RE;
    constexpr int ST = 33;
    __shared__ float RAW[RE * SR];
    __shared__ float T[RE * ST];
    const int tid = threadIdx.x;
    const int tr0 = blockIdx.y * TS, tc0 = blockIdx.x * TS;
    const float* src = in + (long)blockIdx.z * inBatchStride;
    for (int e = tid; e < RE * RE; e += 256) {
        int r = e / RE, c = e % RE;
        int gr = tr0 - (W - 1) + r, gc = tc0 - (W - 1) + c;
        float v = 0.f;
        if (gr >= 0 && gr < IMG && gc >= 0 && gc < IMG) v = src[(long)gr * IMG + gc];
        RAW[r * SR + c] = v;
    }
    __syncthreads();
    for (int e = tid; e < RE * TS; e += 256) {
        int r = e >> 5, j = e & 31;
        float s = 0.f;
#pragma unroll
        for (int k = 0; k < WIN; ++k) s += RAW[r * SR + j + k];
        T[r * ST + j] = s;
    }
    __syncthreads();
    float* dst = out + (long)blockIdx.z * HWSZ;
    for (int e = tid; e < TS * TS; e += 256) {
        int pr = e >> 5, pc = e & 31;
        float s = 0.f;
#pragma unroll
        for (int k = 0; k < WIN; ++k) s += T[(pr + k) * ST + pc];
        float da = RAW[(pr + W - 1) * SR + (pc + W - 1)] - s * (1.0f / NN);
        dst[(long)(tr0 + pr) * IMG + tc0 + pc] = da;
    }
}

template <int W>
__global__ __launch_bounds__(256) void k_sq(const float* __restrict__ in,
                                            float* __restrict__ out) {
    constexpr int TS = 32, WIN = 2 * W, RE = TS + WIN - 1;
    constexpr int SR = RE, ST = 33;
    __shared__ float RAW[RE * SR];
    __shared__ float T[RE * ST];
    const int tid = threadIdx.x;
    const int tr0 = blockIdx.y * TS, tc0 = blockIdx.x * TS;
    const float* src = in + (long)blockIdx.z * HWSZ;
    for (int e = tid; e < RE * RE; e += 256) {
        int r = e / RE, c = e % RE;
        int gr = tr0 - (W - 1) + r, gc = tc0 - (W - 1) + c;
        float v = 0.f;
        if (gr >= 0 && gr < IMG && gc >= 0 && gc < IMG) v = src[(long)gr * IMG + gc];
        RAW[r * SR + c] = v;
    }
    __syncthreads();
    for (int e = tid; e < RE * TS; e += 256) {
        int r = e >> 5, j = e & 31;
        float s = 0.f;
#pragma unroll
        for (int k = 0; k < WIN; ++k) {
            float v = RAW[r * SR + j + k];
            s += v * v;
        }
        T[r * ST + j] = s;
    }
    __syncthreads();
    float* dst = out + (long)blockIdx.z * HWSZ;
    for (int e = tid; e < TS * TS; e += 256) {
        int pr = e >> 5, pc = e & 31;
        float s = 0.f;
#pragma unroll
        for (int k = 0; k < WIN; ++k) s += T[(pr + k) * ST + pc];
        dst[(long)(tr0 + pr) * IMG + tc0 + pc] = s;
    }
}

// ---------------------------------------------------------------------------
// Sliding-window helpers for the full-size (32-image) path.

template <int W> struct WinDims {
    static constexpr int A  = (W + 3) & ~3;
    static constexpr int NU = A + W + 8;              // elements actually used
    static constexpr int NF = (NU + 3) / 4;           // 4-elem chunks loaded
    static constexpr int NV = NF * 4;                 // padded array size
};

template <int W>
__device__ __forceinline__ void loadRowWin(const float* __restrict__ row, int c0,
                                           float* v) {
    constexpr int A = WinDims<W>::A;
    constexpr int NF = WinDims<W>::NF;
#pragma unroll
    for (int f = 0; f < NF; ++f) {
        const int cb = c0 - A + 4 * f;
        if (cb >= 0 && cb + 3 < IMG) {
            const float4 t = *(const float4*)(row + cb);
            v[4 * f + 0] = t.x; v[4 * f + 1] = t.y;
            v[4 * f + 2] = t.z; v[4 * f + 3] = t.w;
        } else {
#pragma unroll
            for (int u = 0; u < 4; ++u) {
                const int c = cb + u;
                v[4 * f + u] = (c >= 0 && c < IMG) ? row[c] : 0.f;
            }
        }
    }
}

template <int W>
__device__ __forceinline__ void loadRowWinH(const half_t* __restrict__ row, int c0,
                                            float* v) {
    constexpr int A = WinDims<W>::A;
    constexpr int NF = WinDims<W>::NF;
#pragma unroll
    for (int f = 0; f < NF; ++f) {
        const int cb = c0 - A + 4 * f;   // multiple of 4 -> 8B aligned
        if (cb >= 0 && cb + 3 < IMG) {
            const half4v t = *(const half4v*)(row + cb);
            v[4 * f + 0] = (float)t[0]; v[4 * f + 1] = (float)t[1];
            v[4 * f + 2] = (float)t[2]; v[4 * f + 3] = (float)t[3];
        } else {
#pragma unroll
            for (int u = 0; u < 4; ++u) {
                const int c = cb + u;
                v[4 * f + u] = (c >= 0 && c < IMG) ? (float)row[c] : 0.f;
            }
        }
    }
}

// ---------------------------------------------------------------------------
// XCD-aware decode for the full-size tile kernels (2048-block flat grids).
__device__ __forceinline__ void xcdDecode(int id, int& z, int& tr0, int& tc0) {
    const int xcd = id & 7, inner = id >> 3;
    z = (xcd << 2) | (inner >> 6);
    const int t = inner & 63;
    tr0 = (t >> 3) * 64;
    tc0 = (t & 7) * 64;
}

// ---------------------------------------------------------------------------
// Fused da kernel (H-box + V-box + da epilogue), 64x64 tile, one barrier.
// grid 2048 x 256 (XCD-swizzled). Used for the w=8 (inp ms) pipeline.
template <int W>
__global__ __launch_bounds__(256) void kDAtile(const float* __restrict__ in,
                                               long sB, long sC,
                                               half_t* __restrict__ out) {
    constexpr int A = WinDims<W>::A;
    constexpr int NV = WinDims<W>::NV;
    constexpr int NRS = 63 + 2 * W;               // staged t rows
    constexpr int LP = 65;                        // float pitch
    constexpr int NN = 4 * W * W;
    __shared__ float T[NRS * LP];
    int z, tr0, tc0;
    xcdDecode(blockIdx.x, z, tr0, tc0);
    const float* img = in + (long)(z >> 3) * sB + (long)(z & 7) * sC;

    // phase 1: t = H-box(raw), rows tr0-W+1 .. tr0+62+W, cols tc0..tc0+63
    for (int e = threadIdx.x; e < NRS * 8; e += 256) {
        const int i = e >> 3, cg = e & 7;
        const int gr = tr0 - W + 1 + i;
        float* dst = &T[i * LP + cg * 8];
        if (gr < 0 || gr >= IMG) {
#pragma unroll
            for (int j = 0; j < 8; ++j) dst[j] = 0.f;
            continue;
        }
        float v[NV];
        loadRowWin<W>(img + (long)gr * IMG, tc0 + cg * 8, v);
        float s = 0.f;
#pragma unroll
        for (int k = A - W + 1; k <= A + W; ++k) s += v[k];
        dst[0] = s;
#pragma unroll
        for (int j = 1; j < 8; ++j) {
            s += v[A + W + j] - v[A - W + j];
            dst[j] = s;
        }
    }
    __syncthreads();

    // phase 2: V-slide + epilogue
    const int c = threadIdx.x & 63, q = threadIdx.x >> 6;
    const int ro0 = q * 16;
    float s = 0.f;
#pragma unroll
    for (int k = 0; k < 2 * W; ++k) s += T[(ro0 + k) * LP + c];
    const float* oz = img + tc0 + c;
    half_t* dz = out + (long)z * HWSZ + tc0 + c;
#pragma unroll
    for (int j = 0; j < 16; ++j) {
        const int r = tr0 + ro0 + j;
        const float o = oz[(long)r * IMG];
        dz[(long)r * IMG] = (half_t)(o - s * (1.0f / NN));
        if (j < 15) s += T[(ro0 + j + 2 * W) * LP + c] - T[(ro0 + j) * LP + c];
    }
}

// ---------------------------------------------------------------------------
// kDAspec: kDAtile<2> on `outputs` + the L_spec 41-tap H-conv fused as a
// third phase (replaces k_spec_h). Phase 3 is the k_spec_h register-window
// body (14 float4 loads, 4 accumulators, identical accumulation order).
// grid 2048 x 256 (XCD-swizzled).
__global__ __launch_bounds__(256) void kDAspec(const float* __restrict__ outputs,
                                               const float* __restrict__ mtf,
                                               half_t* __restrict__ outDA,
                                               float* __restrict__ tmpS) {
    constexpr int W = 2;
    constexpr int A = WinDims<W>::A;
    constexpr int NV = WinDims<W>::NV;
    constexpr int NRS = 63 + 2 * W;               // 67
    constexpr int LP = 65;
    constexpr int NN = 4 * W * W;
    __shared__ float T[NRS * LP];
    __shared__ float vrow[41];
    int z, tr0, tc0;
    xcdDecode(blockIdx.x, z, tr0, tc0);
    const int band = z & 7;
    if (threadIdx.x < 41)
        vrow[threadIdx.x] = mtf[band * 1681 + 20 * 41 + threadIdx.x] /
                            sqrtf(mtf[band * 1681 + 20 * 41 + 20]);
    const float* img = outputs + (long)z * HWSZ;

    // phase 1: t = H-box(raw)
    for (int e = threadIdx.x; e < NRS * 8; e += 256) {
        const int i = e >> 3, cg = e & 7;
        const int gr = tr0 - W + 1 + i;
        float* dst = &T[i * LP + cg * 8];
        if (gr < 0 || gr >= IMG) {
#pragma unroll
            for (int j = 0; j < 8; ++j) dst[j] = 0.f;
            continue;
        }
        float v[NV];
        loadRowWin<W>(img + (long)gr * IMG, tc0 + cg * 8, v);
        float s = 0.f;
#pragma unroll
        for (int k = A - W + 1; k <= A + W; ++k) s += v[k];
        dst[0] = s;
#pragma unroll
        for (int j = 1; j < 8; ++j) {
            s += v[A + W + j] - v[A - W + j];
            dst[j] = s;
        }
    }
    __syncthreads();   // also publishes vrow

    // phase 2: V-slide + da epilogue
    const int c = threadIdx.x & 63, q = threadIdx.x >> 6;
    const int ro0 = q * 16;
    float s = 0.f;
#pragma unroll
    for (int k = 0; k < 2 * W; ++k) s += T[(ro0 + k) * LP + c];
    const float* oz = img + tc0 + c;
    half_t* dz = outDA + (long)z * HWSZ + tc0 + c;
#pragma unroll
    for (int j = 0; j < 16; ++j) {
        const int r = tr0 + ro0 + j;
        const float o = oz[(long)r * IMG];
        dz[(long)r * IMG] = (half_t)(o - s * (1.0f / NN));
        if (j < 15) s += T[(ro0 + j + 2 * W) * LP + c] - T[(ro0 + j) * LP + c];
    }

    // phase 3: spec H-conv, k_spec_h register-window body on the tile.
    {
        const int r = threadIdx.x >> 2, u = threadIdx.x & 3;
        const float* row = img + (long)(tr0 + r) * IMG;
        float v[56];
#pragma unroll
        for (int f = 0; f < 14; ++f) {
            const int cb = tc0 + 16 * u - 20 + 4 * f;
            if (cb >= 0 && cb + 3 < IMG) {
                const float4 t = *(const float4*)(row + cb);
                v[4 * f + 0] = t.x; v[4 * f + 1] = t.y;
                v[4 * f + 2] = t.z; v[4 * f + 3] = t.w;
            } else {
#pragma unroll
                for (int uu = 0; uu < 4; ++uu) {
                    const int cc = cb + uu;
                    v[4 * f + uu] = (cc >= 0 && cc < IMG) ? row[cc] : 0.f;
                }
            }
        }
        float o[4] = {0.f, 0.f, 0.f, 0.f};
#pragma unroll
        for (int j = 0; j < 41; ++j) {
            const float w = vrow[j];
#pragma unroll
            for (int uu = 0; uu < 4; ++uu) o[uu] += w * v[2 + 4 * uu + j];
        }
        float* ts = tmpS + ((long)z * IMG + tr0 + r) * 128 + (tc0 >> 2) + 4 * u;
        *(float4*)ts = make_float4(o[0], o[1], o[2], o[3]);
    }
}

// ---------------------------------------------------------------------------
// Fused product + H-box staging: per 64x64 tile, H-box of (da*dshared, da*da)
// rows into LDS as packed half2(p1,p2).
template <int W>
__device__ __forceinline__ void stageProducts(const half_t* __restrict__ daz,
                                              const float* __restrict__ dsz,
                                              int tr0, int tc0,
                                              unsigned int* L) {
    constexpr int A = WinDims<W>::A;
    constexpr int NU = WinDims<W>::NU;
    constexpr int NV = WinDims<W>::NV;
    constexpr int NRS = 63 + 2 * W;               // staged product rows
    constexpr int LP = 65;                        // uint pitch (4B units)
    for (int e = threadIdx.x; e < NRS * 8; e += 256) {
        const int i = e >> 3, cg = e & 7;
        const int gr = tr0 - W + 1 + i;
        const int c0 = tc0 + cg * 8;
        unsigned int* dst = L + i * LP + cg * 8;
        if (gr < 0 || gr >= IMG) {
#pragma unroll
            for (int j = 0; j < 8; ++j) dst[j] = 0u;
            continue;
        }
        float va[NV], vs[NV];
        loadRowWinH<W>(daz + (long)gr * IMG, c0, va);
        loadRowWin<W>(dsz + (long)gr * IMG, c0, vs);
        float p1[NV], p2[NV];
#pragma unroll
        for (int k = 0; k < NU; ++k) { p1[k] = va[k] * vs[k]; p2[k] = va[k] * va[k]; }
        float s1 = 0.f, s2 = 0.f;
#pragma unroll
        for (int k = A - W + 1; k <= A + W; ++k) { s1 += p1[k]; s2 += p2[k]; }
#pragma unroll
        for (int j = 0; j < 8; ++j) {
            half2v h;
            h[0] = (half_t)s1; h[1] = (half_t)s2;
            dst[j] = __builtin_bit_cast(unsigned int, h);
            if (j < 7) {
                s1 += p1[A + W + 1 + j] - p1[A - W + 1 + j];
                s2 += p2[A + W + 1 + j] - p2[A - W + 1 + j];
            }
        }
    }
}

// ---------------------------------------------------------------------------
// Fully fused structural kernel (round-9 verified body) + absorbed L_spec
// V-pass tail. Structure: stage both product pipelines -> one barrier ->
// V8(thr in regs) -> V2(Y) -> Y-reduce -> spec V-conv over tmpS + reduce.
// The spec tail is pure extra independent memory work dropped into this
// latency-bound kernel's slack (wall 55us vs ~27us VALU busy): 41 strided
// scalar loads/thread (16 threads share each 64B tmpS line), identical
// per-output accumulation order to the old k_spec_v -> per-output bitwise
// equal; only float-partial grouping of the block reduction differs.
// LDS 38.6 KB -> 4 blocks/CU. grid 2048 x 256 (XCD-swizzled).
__global__ __launch_bounds__(256, 4) void kFusedXY(
    const half_t* __restrict__ daMS,
    const float* __restrict__ daPAN,
    const float* __restrict__ saa,
    const half_t* __restrict__ daOUT,
    const float* __restrict__ dbPAN,
    const float* __restrict__ sbb,
    const float* __restrict__ tmpS,
    const float* __restrict__ labels,
    const float* __restrict__ spec,
    const float* __restrict__ mtf,
    double* __restrict__ acc) {
    constexpr int LP = 65;
    constexpr int NRS8 = 63 + 16;                 // 79 (w=8)
    constexpr int NRS2 = 63 + 4;                  // 67 (w=2)
    __shared__ unsigned int L8[NRS8 * LP];
    __shared__ unsigned int L2b[NRS2 * LP];
    __shared__ double redY[4];
    __shared__ double redT[4];
    __shared__ double redM[4];
    __shared__ float ucol[41];
    int z, tr0, tc0;
    xcdDecode(blockIdx.x, z, tr0, tc0);
    const int b = z >> 3, band = z & 7;
    const int c = threadIdx.x & 63, q = threadIdx.x >> 6;
    const int ro0 = q * 16;
    if (threadIdx.x < 41)
        ucol[threadIdx.x] = mtf[band * 1681 + threadIdx.x * 41 + 20] /
                            sqrtf(mtf[band * 1681 + 20 * 41 + 20]);

    // ---- stage both pipelines, then one barrier -------------------------
    stageProducts<8>(daMS + (long)z * HWSZ, daPAN + (long)b * HWSZ, tr0, tc0, L8);
    stageProducts<2>(daOUT + (long)z * HWSZ, dbPAN + (long)b * HWSZ, tr0, tc0, L2b);
    __syncthreads();   // publishes L8, L2b, ucol

    float thrv[16];
    {   // ---------------- w = 8: thr ----------------
        constexpr int W = 8;
        float s1 = 0.f, s2 = 0.f;
#pragma unroll
        for (int k = 0; k < 2 * W; ++k) {
            const half2v h = __builtin_bit_cast(half2v, L8[(ro0 + k) * LP + c]);
            s1 += (float)h[0]; s2 += (float)h[1];
        }
        const float* sz = saa + (long)b * HWSZ + tc0 + c;
#pragma unroll
        for (int j = 0; j < 16; ++j) {
            const int r = tr0 + ro0 + j;
            const float sa = sz[(long)r * IMG];
            const float den = sqrtf(fmaxf(sa * s2, 0.f)) + 1e-20f;
            thrv[j] = 1.0f - s1 / den;
            if (j < 15) {
                const half2v ha = __builtin_bit_cast(half2v, L8[(ro0 + j + 2 * W) * LP + c]);
                const half2v hs = __builtin_bit_cast(half2v, L8[(ro0 + j) * LP + c]);
                s1 += (float)ha[0] - (float)hs[0];
                s2 += (float)ha[1] - (float)hs[1];
            }
        }
    }
    double ysum = 0.0;
    {   // ---------------- w = 2: X vs thr, Y ---------- (no barrier needed)
        constexpr int W = 2;
        float s1 = 0.f, s2 = 0.f;
#pragma unroll
        for (int k = 0; k < 2 * W; ++k) {
            const half2v h = __builtin_bit_cast(half2v, L2b[(ro0 + k) * LP + c]);
            s1 += (float)h[0]; s2 += (float)h[1];
        }
        const float* sz = sbb + (long)b * HWSZ + tc0 + c;
#pragma unroll
        for (int j = 0; j < 16; ++j) {
            const float sb = sz[(long)(tr0 + ro0 + j) * IMG];
            const float den = sqrtf(fmaxf(s2 * sb, 0.f)) + 1e-20f;
            const float Xc = s1 / den;
            const float X = 1.0f - fmaxf(Xc, -1.0f);
            if (X > thrv[j]) ysum += (double)X;
            if (j < 15) {
                const half2v ha = __builtin_bit_cast(half2v, L2b[(ro0 + j + 2 * W) * LP + c]);
                const half2v ht = __builtin_bit_cast(half2v, L2b[(ro0 + j) * LP + c]);
                s1 += (float)ha[0] - (float)ht[0];
                s2 += (float)ha[1] - (float)ht[1];
            }
        }
    }
    blockReduceAtomicAdd(ysum, acc + 2, redY);

    // ---- L_spec tail: 41-row V-conv over tmpS + |.|-reduce --------------
    // Thread (rs = tid>>4, qc = tid&15) -> output (gr, gc) =
    // (tr0+2+4*rs, tc0+2+4*qc); same ascending-i accumulation order as the
    // old k_spec_v -> per-output bitwise identical.
    {
        const int rs = threadIdx.x >> 4, qc = threadIdx.x & 15;
        const int gr = tr0 + 2 + 4 * rs;
        const int gc = tc0 + 2 + 4 * qc;
        const int sc = (tc0 >> 2) + qc;
        const float* base = tmpS + (long)z * IMG * 128 + sc;
        const int rbase = gr - 20;
        float o = 0.f;
        if (rbase >= 0 && rbase + 40 < IMG) {
#pragma unroll
            for (int i = 0; i < 41; ++i)
                o += ucol[i] * base[(long)(rbase + i) * 128];
        } else {
            for (int i = 0; i < 41; ++i) {
                const int r = rbase + i;
                if (r >= 0 && r < IMG) o += ucol[i] * base[(long)r * 128];
            }
        }
        const float m = spec[(long)band * HWSZ + (long)gr * IMG + gc];
        const float y = labels[((long)b * 9 + band) * HWSZ + (long)gr * IMG + gc];
        const float t = fabsf(o * m - y * m);
        blockReduceAtomicAdd((double)t, acc + 0, redT);
        blockReduceAtomicAdd((double)m, acc + 1, redM);
    }
}

__global__ void k_final(const double* __restrict__ acc, float* __restrict__ out) {
    double lspec = acc[0] / acc[1];
    double lstruct = acc[2] / (double)(NBATCH * NBANDS * HWSZ);
    out[0] = (float)(lspec + 0.25 * lstruct);
}

// ---------------------------------------------------------------------------
extern "C" void kernel_launch(void* const* d_in, const int* in_sizes, int n_in,
                              void* d_out, int out_size, void* d_ws, size_t ws_size,
                              hipStream_t stream) {
    const float* outputs = (const float*)d_in[0];   // (4,8,512,512)
    const float* labels  = (const float*)d_in[1];   // (4,9,512,512)
    const float* inp     = (const float*)d_in[2];   // (4,9,512,512)
    const float* mtf     = (const float*)d_in[3];   // (8,1,41,41)
    const float* spec    = (const float*)d_in[4];   // (1,8,512,512)
    float* out = (float*)d_out;

    const long IMGB = (long)HWSZ;     // one image in elements
    char* ws = (char*)d_ws;
    double* acc    = (double*)ws;                    // 4 doubles
    float* panf    = (float*)(ws + 1024);            // 4 imgs fp32
    float* tmpH    = panf   + NBATCH * IMGB;         // 4 imgs
    float* da_pan8 = tmpH   + NBATCH * IMGB;         // 4 imgs
    float* saa8    = da_pan8 + NBATCH * IMGB;        // 4 imgs
    float* db_pan2 = saa8   + NBATCH * IMGB;         // 4 imgs
    float* sbb2    = db_pan2 + NBATCH * IMGB;        // 4 imgs
    float* tmpS    = sbb2   + NBATCH * IMGB;         // 8 imgs fp32
    half_t* hDA8   = (half_t*)(tmpS + 8 * IMGB);     // 32 imgs half: da_ms  (w=8)
    half_t* hDA2   = hDA8 + 32 * IMGB;               // 32 imgs half: da_out (w=2)

    hipMemsetAsync(acc, 0, 4 * sizeof(double), stream);

    // --- per-batch shared fields (fp32) ----------------------------------
    k_pan_h<<<dim3(2, 512, NBATCH), 256, 0, stream>>>(inp, mtf, tmpH);
    k_pan_v<<<dim3(2, 512, NBATCH), 256, 0, stream>>>(tmpH, mtf, panf);
    k_da<8><<<dim3(16, 16, NBATCH), 256, 0, stream>>>(panf, (long)HWSZ, da_pan8);
    k_sq<8><<<dim3(16, 16, NBATCH), 256, 0, stream>>>(da_pan8, saa8);
    k_da<2><<<dim3(16, 16, NBATCH), 256, 0, stream>>>(labels + 8 * IMGB,
                                                      (long)9 * HWSZ, db_pan2);
    k_sq<2><<<dim3(16, 16, NBATCH), 256, 0, stream>>>(db_pan2, sbb2);

    // --- da fields (w=8) + fused da/spec-H (w=2) --------------------------
    kDAtile<8><<<2048, 256, 0, stream>>>(inp, 9 * IMGB, IMGB, hDA8);
    kDAspec<<<2048, 256, 0, stream>>>(outputs, mtf, hDA2, tmpS);

    // --- fused products + box + thr + X + Y reduce + spec V-pass ----------
    kFusedXY<<<2048, 256, 0, stream>>>(hDA8, da_pan8, saa8,
                                       hDA2, db_pan2, sbb2,
                                       tmpS, labels, spec, mtf, acc);

    k_final<<<1, 1, 0, stream>>>(acc, out);
}

// Round 13
// 291.758 us; speedup vs baseline: 1.0656x; 1.0656x over previous
//
#include <hip/hip_runtime.h>
#include <hip/hip_bf16.h>

// Problem constants
#define HWSZ   262144   // 512*512
#define IMG    512
#define NBATCH 4
#define NBANDS 8

typedef _Float16 half_t;
typedef _Float16 half2v __attribute__((ext_vector_type(2)));
typedef _Float16 half4v __attribute__((ext_vector_type(4)));
typedef _Float16 half8v __attribute__((ext_vector_type(8)));

// ---------------------------------------------------------------------------
// Block-level reduction: wave shuffle + LDS + one double atomic per block.
__device__ __forceinline__ void blockReduceAtomicAdd(double v, double* target,
                                                     double* red) {
    for (int off = 32; off > 0; off >>= 1) v += __shfl_down(v, off, 64);
    const int wave = threadIdx.x >> 6, lane = threadIdx.x & 63;
    if (lane == 0) red[wave] = v;
    __syncthreads();
    if (threadIdx.x == 0) atomicAdd(target, red[0] + red[1] + red[2] + red[3]);
}

// ---------------------------------------------------------------------------
// Fused pan smoothing (edge-clamped 41x41 separable): H-conv of 72 clamped
// rows into LDS (register window, 8 outputs/unit), barrier, 41-tap V-conv.
// Accumulation orders identical to the old k_pan_h / k_pan_v pair ->
// bitwise-identical panf (verified: round-8 bench passed, absmax 0.0).
// grid (16,16,4) x 256.
__global__ __launch_bounds__(256) void kPan(const float* __restrict__ inp,
                                            const float* __restrict__ mtf,
                                            float* __restrict__ panf) {
    constexpr int TS = 32, NR = TS + 40, PT = 33;
    __shared__ float TH[NR * PT];
    __shared__ float vr[41], uc[41];
    const int tid = threadIdx.x;
    const int b = blockIdx.z, tr0 = blockIdx.y * TS, tc0 = blockIdx.x * TS;
    if (tid < 41) {
        const float cen = sqrtf(mtf[20 * 41 + 20]);
        vr[tid] = mtf[20 * 41 + tid] / cen;
        uc[tid] = mtf[tid * 41 + 20] / cen;
    }
    __syncthreads();
    const float* pan = inp + ((long)b * 9 + 8) * HWSZ;

    // phase 1: TH[i][c] = Hconv(row clamp(tr0-20+i), col tc0+c)
    for (int e = tid; e < NR * 4; e += 256) {
        const int i = e >> 2, cg = e & 3;
        const int gr = min(max(tr0 - 20 + i, 0), IMG - 1);
        const int c0 = tc0 + cg * 8;
        const float* row = pan + (long)gr * IMG;
        float v[48];
#pragma unroll
        for (int f = 0; f < 12; ++f) {
            const int cb = c0 - 20 + 4 * f;
            if (cb >= 0 && cb + 3 < IMG) {
                const float4 t = *(const float4*)(row + cb);
                v[4 * f + 0] = t.x; v[4 * f + 1] = t.y;
                v[4 * f + 2] = t.z; v[4 * f + 3] = t.w;
            } else {
#pragma unroll
                for (int u = 0; u < 4; ++u) {
                    const int cc = min(max(cb + u, 0), IMG - 1);
                    v[4 * f + u] = row[cc];
                }
            }
        }
        float o[8] = {0.f, 0.f, 0.f, 0.f, 0.f, 0.f, 0.f, 0.f};
#pragma unroll
        for (int j = 0; j < 41; ++j) {
            const float w = vr[j];
#pragma unroll
            for (int u = 0; u < 8; ++u) o[u] += w * v[u + j];
        }
        float* dst = &TH[i * PT + cg * 8];
#pragma unroll
        for (int u = 0; u < 8; ++u) dst[u] = o[u];
    }
    __syncthreads();

    // phase 2: V-conv, 4 rows/thread
    const int c = tid & 31, q = tid >> 5;
    const int rr0 = q * 4;
    float* dst = panf + (long)b * HWSZ + tc0 + c;
#pragma unroll
    for (int j = 0; j < 4; ++j) {
        float s = 0.f;
#pragma unroll
        for (int i = 0; i < 41; ++i) s += uc[i] * TH[(rr0 + j + i) * PT + c];
        dst[(long)(tr0 + rr0 + j) * IMG] = s;
    }
}

// ---------------------------------------------------------------------------
// Small-field (4-image) helpers, LDS tile based (cheap at this size).
template <int W>
__global__ __launch_bounds__(256) void k_da(const float* __restrict__ in,
                                            long inBatchStride,
                                            float* __restrict__ out) {
    constexpr int TS = 32, WIN = 2 * W, NN = 4 * W * W, RE = TS + WIN - 1;
    constexpr int SR = RE;
    constexpr int ST = 33;
    __shared__ float RAW[RE * SR];
    __shared__ float T[RE * ST];
    const int tid = threadIdx.x;
    const int tr0 = blockIdx.y * TS, tc0 = blockIdx.x * TS;
    const float* src = in + (long)blockIdx.z * inBatchStride;
    for (int e = tid; e < RE * RE; e += 256) {
        int r = e / RE, c = e % RE;
        int gr = tr0 - (W - 1) + r, gc = tc0 - (W - 1) + c;
        float v = 0.f;
        if (gr >= 0 && gr < IMG && gc >= 0 && gc < IMG) v = src[(long)gr * IMG + gc];
        RAW[r * SR + c] = v;
    }
    __syncthreads();
    for (int e = tid; e < RE * TS; e += 256) {
        int r = e >> 5, j = e & 31;
        float s = 0.f;
#pragma unroll
        for (int k = 0; k < WIN; ++k) s += RAW[r * SR + j + k];
        T[r * ST + j] = s;
    }
    __syncthreads();
    float* dst = out + (long)blockIdx.z * HWSZ;
    for (int e = tid; e < TS * TS; e += 256) {
        int pr = e >> 5, pc = e & 31;
        float s = 0.f;
#pragma unroll
        for (int k = 0; k < WIN; ++k) s += T[(pr + k) * ST + pc];
        float da = RAW[(pr + W - 1) * SR + (pc + W - 1)] - s * (1.0f / NN);
        dst[(long)(tr0 + pr) * IMG + tc0 + pc] = da;
    }
}

template <int W>
__global__ __launch_bounds__(256) void k_sq(const float* __restrict__ in,
                                            float* __restrict__ out) {
    constexpr int TS = 32, WIN = 2 * W, RE = TS + WIN - 1;
    constexpr int SR = RE, ST = 33;
    __shared__ float RAW[RE * SR];
    __shared__ float T[RE * ST];
    const int tid = threadIdx.x;
    const int tr0 = blockIdx.y * TS, tc0 = blockIdx.x * TS;
    const float* src = in + (long)blockIdx.z * HWSZ;
    for (int e = tid; e < RE * RE; e += 256) {
        int r = e / RE, c = e % RE;
        int gr = tr0 - (W - 1) + r, gc = tc0 - (W - 1) + c;
        float v = 0.f;
        if (gr >= 0 && gr < IMG && gc >= 0 && gc < IMG) v = src[(long)gr * IMG + gc];
        RAW[r * SR + c] = v;
    }
    __syncthreads();
    for (int e = tid; e < RE * TS; e += 256) {
        int r = e >> 5, j = e & 31;
        float s = 0.f;
#pragma unroll
        for (int k = 0; k < WIN; ++k) {
            float v = RAW[r * SR + j + k];
            s += v * v;
        }
        T[r * ST + j] = s;
    }
    __syncthreads();
    float* dst = out + (long)blockIdx.z * HWSZ;
    for (int e = tid; e < TS * TS; e += 256) {
        int pr = e >> 5, pc = e & 31;
        float s = 0.f;
#pragma unroll
        for (int k = 0; k < WIN; ++k) s += T[(pr + k) * ST + pc];
        dst[(long)(tr0 + pr) * IMG + tc0 + pc] = s;
    }
}

// ---------------------------------------------------------------------------
// Sliding-window helpers for the full-size (32-image) path.

template <int W> struct WinDims {
    static constexpr int A  = (W + 3) & ~3;
    static constexpr int NU = A + W + 8;              // elements actually used
    static constexpr int NF = (NU + 3) / 4;           // 4-elem chunks loaded
    static constexpr int NV = NF * 4;                 // padded array size
};

template <int W>
__device__ __forceinline__ void loadRowWin(const float* __restrict__ row, int c0,
                                           float* v) {
    constexpr int A = WinDims<W>::A;
    constexpr int NF = WinDims<W>::NF;
#pragma unroll
    for (int f = 0; f < NF; ++f) {
        const int cb = c0 - A + 4 * f;
        if (cb >= 0 && cb + 3 < IMG) {
            const float4 t = *(const float4*)(row + cb);
            v[4 * f + 0] = t.x; v[4 * f + 1] = t.y;
            v[4 * f + 2] = t.z; v[4 * f + 3] = t.w;
        } else {
#pragma unroll
            for (int u = 0; u < 4; ++u) {
                const int c = cb + u;
                v[4 * f + u] = (c >= 0 && c < IMG) ? row[c] : 0.f;
            }
        }
    }
}

template <int W>
__device__ __forceinline__ void loadRowWinH(const half_t* __restrict__ row, int c0,
                                            float* v) {
    constexpr int A = WinDims<W>::A;
    constexpr int NF = WinDims<W>::NF;
#pragma unroll
    for (int f = 0; f < NF; ++f) {
        const int cb = c0 - A + 4 * f;   // multiple of 4 -> 8B aligned
        if (cb >= 0 && cb + 3 < IMG) {
            const half4v t = *(const half4v*)(row + cb);
            v[4 * f + 0] = (float)t[0]; v[4 * f + 1] = (float)t[1];
            v[4 * f + 2] = (float)t[2]; v[4 * f + 3] = (float)t[3];
        } else {
#pragma unroll
            for (int u = 0; u < 4; ++u) {
                const int c = cb + u;
                v[4 * f + u] = (c >= 0 && c < IMG) ? (float)row[c] : 0.f;
            }
        }
    }
}

// ---------------------------------------------------------------------------
// XCD-aware decode for the full-size tile kernels (2048-block flat grids).
__device__ __forceinline__ void xcdDecode(int id, int& z, int& tr0, int& tc0) {
    const int xcd = id & 7, inner = id >> 3;
    z = (xcd << 2) | (inner >> 6);
    const int t = inner & 63;
    tr0 = (t >> 3) * 64;
    tc0 = (t & 7) * 64;
}

// ---------------------------------------------------------------------------
// Fused da kernel (H-box + V-box + da epilogue), 64x64 tile, one barrier.
// grid 2048 x 256 (XCD-swizzled). Used for the w=8 (inp ms) pipeline.
template <int W>
__global__ __launch_bounds__(256) void kDAtile(const float* __restrict__ in,
                                               long sB, long sC,
                                               half_t* __restrict__ out) {
    constexpr int A = WinDims<W>::A;
    constexpr int NV = WinDims<W>::NV;
    constexpr int NRS = 63 + 2 * W;               // staged t rows
    constexpr int LP = 65;                        // float pitch
    constexpr int NN = 4 * W * W;
    __shared__ float T[NRS * LP];
    int z, tr0, tc0;
    xcdDecode(blockIdx.x, z, tr0, tc0);
    const float* img = in + (long)(z >> 3) * sB + (long)(z & 7) * sC;

    // phase 1: t = H-box(raw), rows tr0-W+1 .. tr0+62+W, cols tc0..tc0+63
    for (int e = threadIdx.x; e < NRS * 8; e += 256) {
        const int i = e >> 3, cg = e & 7;
        const int gr = tr0 - W + 1 + i;
        float* dst = &T[i * LP + cg * 8];
        if (gr < 0 || gr >= IMG) {
#pragma unroll
            for (int j = 0; j < 8; ++j) dst[j] = 0.f;
            continue;
        }
        float v[NV];
        loadRowWin<W>(img + (long)gr * IMG, tc0 + cg * 8, v);
        float s = 0.f;
#pragma unroll
        for (int k = A - W + 1; k <= A + W; ++k) s += v[k];
        dst[0] = s;
#pragma unroll
        for (int j = 1; j < 8; ++j) {
            s += v[A + W + j] - v[A - W + j];
            dst[j] = s;
        }
    }
    __syncthreads();

    // phase 2: V-slide + epilogue
    const int c = threadIdx.x & 63, q = threadIdx.x >> 6;
    const int ro0 = q * 16;
    float s = 0.f;
#pragma unroll
    for (int k = 0; k < 2 * W; ++k) s += T[(ro0 + k) * LP + c];
    const float* oz = img + tc0 + c;
    half_t* dz = out + (long)z * HWSZ + tc0 + c;
#pragma unroll
    for (int j = 0; j < 16; ++j) {
        const int r = tr0 + ro0 + j;
        const float o = oz[(long)r * IMG];
        dz[(long)r * IMG] = (half_t)(o - s * (1.0f / NN));
        if (j < 15) s += T[(ro0 + j + 2 * W) * LP + c] - T[(ro0 + j) * LP + c];
    }
}

// ---------------------------------------------------------------------------
// kDAspec: kDAtile<2> on `outputs` + the L_spec 41-tap H-conv fused as a
// third phase (replaces k_spec_h). Phase 3 is the k_spec_h register-window
// body (14 float4 loads, 4 accumulators, identical accumulation order).
// grid 2048 x 256 (XCD-swizzled).
__global__ __launch_bounds__(256) void kDAspec(const float* __restrict__ outputs,
                                               const float* __restrict__ mtf,
                                               half_t* __restrict__ outDA,
                                               float* __restrict__ tmpS) {
    constexpr int W = 2;
    constexpr int A = WinDims<W>::A;
    constexpr int NV = WinDims<W>::NV;
    constexpr int NRS = 63 + 2 * W;               // 67
    constexpr int LP = 65;
    constexpr int NN = 4 * W * W;
    __shared__ float T[NRS * LP];
    __shared__ float vrow[41];
    int z, tr0, tc0;
    xcdDecode(blockIdx.x, z, tr0, tc0);
    const int band = z & 7;
    if (threadIdx.x < 41)
        vrow[threadIdx.x] = mtf[band * 1681 + 20 * 41 + threadIdx.x] /
                            sqrtf(mtf[band * 1681 + 20 * 41 + 20]);
    const float* img = outputs + (long)z * HWSZ;

    // phase 1: t = H-box(raw)
    for (int e = threadIdx.x; e < NRS * 8; e += 256) {
        const int i = e >> 3, cg = e & 7;
        const int gr = tr0 - W + 1 + i;
        float* dst = &T[i * LP + cg * 8];
        if (gr < 0 || gr >= IMG) {
#pragma unroll
            for (int j = 0; j < 8; ++j) dst[j] = 0.f;
            continue;
        }
        float v[NV];
        loadRowWin<W>(img + (long)gr * IMG, tc0 + cg * 8, v);
        float s = 0.f;
#pragma unroll
        for (int k = A - W + 1; k <= A + W; ++k) s += v[k];
        dst[0] = s;
#pragma unroll
        for (int j = 1; j < 8; ++j) {
            s += v[A + W + j] - v[A - W + j];
            dst[j] = s;
        }
    }
    __syncthreads();   // also publishes vrow

    // phase 2: V-slide + da epilogue
    const int c = threadIdx.x & 63, q = threadIdx.x >> 6;
    const int ro0 = q * 16;
    float s = 0.f;
#pragma unroll
    for (int k = 0; k < 2 * W; ++k) s += T[(ro0 + k) * LP + c];
    const float* oz = img + tc0 + c;
    half_t* dz = outDA + (long)z * HWSZ + tc0 + c;
#pragma unroll
    for (int j = 0; j < 16; ++j) {
        const int r = tr0 + ro0 + j;
        const float o = oz[(long)r * IMG];
        dz[(long)r * IMG] = (half_t)(o - s * (1.0f / NN));
        if (j < 15) s += T[(ro0 + j + 2 * W) * LP + c] - T[(ro0 + j) * LP + c];
    }

    // phase 3: spec H-conv, k_spec_h register-window body on the tile.
    {
        const int r = threadIdx.x >> 2, u = threadIdx.x & 3;
        const float* row = img + (long)(tr0 + r) * IMG;
        float v[56];
#pragma unroll
        for (int f = 0; f < 14; ++f) {
            const int cb = tc0 + 16 * u - 20 + 4 * f;
            if (cb >= 0 && cb + 3 < IMG) {
                const float4 t = *(const float4*)(row + cb);
                v[4 * f + 0] = t.x; v[4 * f + 1] = t.y;
                v[4 * f + 2] = t.z; v[4 * f + 3] = t.w;
            } else {
#pragma unroll
                for (int uu = 0; uu < 4; ++uu) {
                    const int cc = cb + uu;
                    v[4 * f + uu] = (cc >= 0 && cc < IMG) ? row[cc] : 0.f;
                }
            }
        }
        float o[4] = {0.f, 0.f, 0.f, 0.f};
#pragma unroll
        for (int j = 0; j < 41; ++j) {
            const float w = vrow[j];
#pragma unroll
            for (int uu = 0; uu < 4; ++uu) o[uu] += w * v[2 + 4 * uu + j];
        }
        float* ts = tmpS + ((long)z * IMG + tr0 + r) * 128 + (tc0 >> 2) + 4 * u;
        *(float4*)ts = make_float4(o[0], o[1], o[2], o[3]);
    }
}

// ---------------------------------------------------------------------------
// Fused product + H-box staging: per 64x64 tile, H-box of (da*dshared, da*da)
// rows into LDS as packed half2(p1,p2).
template <int W>
__device__ __forceinline__ void stageProducts(const half_t* __restrict__ daz,
                                              const float* __restrict__ dsz,
                                              int tr0, int tc0,
                                              unsigned int* L) {
    constexpr int A = WinDims<W>::A;
    constexpr int NU = WinDims<W>::NU;
    constexpr int NV = WinDims<W>::NV;
    constexpr int NRS = 63 + 2 * W;               // staged product rows
    constexpr int LP = 65;                        // uint pitch (4B units)
    for (int e = threadIdx.x; e < NRS * 8; e += 256) {
        const int i = e >> 3, cg = e & 7;
        const int gr = tr0 - W + 1 + i;
        const int c0 = tc0 + cg * 8;
        unsigned int* dst = L + i * LP + cg * 8;
        if (gr < 0 || gr >= IMG) {
#pragma unroll
            for (int j = 0; j < 8; ++j) dst[j] = 0u;
            continue;
        }
        float va[NV], vs[NV];
        loadRowWinH<W>(daz + (long)gr * IMG, c0, va);
        loadRowWin<W>(dsz + (long)gr * IMG, c0, vs);
        float p1[NV], p2[NV];
#pragma unroll
        for (int k = 0; k < NU; ++k) { p1[k] = va[k] * vs[k]; p2[k] = va[k] * va[k]; }
        float s1 = 0.f, s2 = 0.f;
#pragma unroll
        for (int k = A - W + 1; k <= A + W; ++k) { s1 += p1[k]; s2 += p2[k]; }
#pragma unroll
        for (int j = 0; j < 8; ++j) {
            half2v h;
            h[0] = (half_t)s1; h[1] = (half_t)s2;
            dst[j] = __builtin_bit_cast(unsigned int, h);
            if (j < 7) {
                s1 += p1[A + W + 1 + j] - p1[A - W + 1 + j];
                s2 += p2[A + W + 1 + j] - p2[A - W + 1 + j];
            }
        }
    }
}

// ---------------------------------------------------------------------------
// Fully fused structural kernel, single-barrier schedule: stage BOTH product
// pipelines (separate LDS buffers) -> one sync -> V8(thr in regs) -> V2(Y).
// LDS 38 KB -> 4 blocks/CU. grid 2048 x 256 (XCD-swizzled).
__global__ __launch_bounds__(256, 4) void kFusedXY(
    const half_t* __restrict__ daMS,
    const float* __restrict__ daPAN,
    const float* __restrict__ saa,
    const half_t* __restrict__ daOUT,
    const float* __restrict__ dbPAN,
    const float* __restrict__ sbb,
    double* __restrict__ acc) {
    constexpr int LP = 65;
    constexpr int NRS8 = 63 + 16;                 // 79 (w=8)
    constexpr int NRS2 = 63 + 4;                  // 67 (w=2)
    __shared__ unsigned int L8[NRS8 * LP];
    __shared__ unsigned int L2b[NRS2 * LP];
    __shared__ double red[4];
    int z, tr0, tc0;
    xcdDecode(blockIdx.x, z, tr0, tc0);
    const int b = z >> 3;
    const int c = threadIdx.x & 63, q = threadIdx.x >> 6;
    const int ro0 = q * 16;

    // ---- stage both pipelines, then one barrier -------------------------
    stageProducts<8>(daMS + (long)z * HWSZ, daPAN + (long)b * HWSZ, tr0, tc0, L8);
    stageProducts<2>(daOUT + (long)z * HWSZ, dbPAN + (long)b * HWSZ, tr0, tc0, L2b);
    __syncthreads();

    float thrv[16];
    {   // ---------------- w = 8: thr ----------------
        constexpr int W = 8;
        float s1 = 0.f, s2 = 0.f;
#pragma unroll
        for (int k = 0; k < 2 * W; ++k) {
            const half2v h = __builtin_bit_cast(half2v, L8[(ro0 + k) * LP + c]);
            s1 += (float)h[0]; s2 += (float)h[1];
        }
        const float* sz = saa + (long)b * HWSZ + tc0 + c;
#pragma unroll
        for (int j = 0; j < 16; ++j) {
            const int r = tr0 + ro0 + j;
            const float sa = sz[(long)r * IMG];
            const float den = sqrtf(fmaxf(sa * s2, 0.f)) + 1e-20f;
            thrv[j] = 1.0f - s1 / den;
            if (j < 15) {
                const half2v ha = __builtin_bit_cast(half2v, L8[(ro0 + j + 2 * W) * LP + c]);
                const half2v hs = __builtin_bit_cast(half2v, L8[(ro0 + j) * LP + c]);
                s1 += (float)ha[0] - (float)hs[0];
                s2 += (float)ha[1] - (float)hs[1];
            }
        }
    }
    double ysum = 0.0;
    {   // ---------------- w = 2: X vs thr, Y ---------- (no barrier needed)
        constexpr int W = 2;
        float s1 = 0.f, s2 = 0.f;
#pragma unroll
        for (int k = 0; k < 2 * W; ++k) {
            const half2v h = __builtin_bit_cast(half2v, L2b[(ro0 + k) * LP + c]);
            s1 += (float)h[0]; s2 += (float)h[1];
        }
        const float* sz = sbb + (long)b * HWSZ + tc0 + c;
#pragma unroll
        for (int j = 0; j < 16; ++j) {
            const float sb = sz[(long)(tr0 + ro0 + j) * IMG];
            const float den = sqrtf(fmaxf(s2 * sb, 0.f)) + 1e-20f;
            const float Xc = s1 / den;
            const float X = 1.0f - fmaxf(Xc, -1.0f);
            if (X > thrv[j]) ysum += (double)X;
            if (j < 15) {
                const half2v ha = __builtin_bit_cast(half2v, L2b[(ro0 + j + 2 * W) * LP + c]);
                const half2v hs = __builtin_bit_cast(half2v, L2b[(ro0 + j) * LP + c]);
                s1 += (float)ha[0] - (float)hs[0];
                s2 += (float)ha[1] - (float)hs[1];
            }
        }
    }
    blockReduceAtomicAdd(ysum, acc + 2, red);
}

// ---------------------------------------------------------------------------
// L_spec V pass + reduce (H pass is fused into kDAspec).
__global__ __launch_bounds__(256) void k_spec_v(const float* __restrict__ tmpS,
                                                const float* __restrict__ labels,
                                                const float* __restrict__ spec,
                                                const float* __restrict__ mtf,
                                                double* __restrict__ acc) {
    __shared__ double redT[4];
    __shared__ double redM[4];
    __shared__ float ucol[41];
    const int g = blockIdx.x * 256 + threadIdx.x;
    const int q = g & 31, rs = (g >> 5) & 127, z = g >> 12;   // z uniform/block
    const int b = z >> 3, band = z & 7;
    if (threadIdx.x < 41)
        ucol[threadIdx.x] = mtf[band * 1681 + threadIdx.x * 41 + 20] /
                            sqrtf(mtf[band * 1681 + 20 * 41 + 20]);
    __syncthreads();
    const float* base = tmpS + (long)z * IMG * 128 + 4 * q;
    const int rbase = 4 * rs - 18;
    float o[4] = {0.f, 0.f, 0.f, 0.f};
    if (rbase >= 0 && rbase + 40 < IMG) {
#pragma unroll
        for (int i = 0; i < 41; ++i) {
            const float4 v = *(const float4*)(base + (long)(rbase + i) * 128);
            const float w = ucol[i];
            o[0] += w * v.x; o[1] += w * v.y; o[2] += w * v.z; o[3] += w * v.w;
        }
    } else {
        for (int i = 0; i < 41; ++i) {
            const int r = rbase + i;
            if (r >= 0 && r < IMG) {
                const float4 v = *(const float4*)(base + (long)r * 128);
                const float w = ucol[i];
                o[0] += w * v.x; o[1] += w * v.y; o[2] += w * v.z; o[3] += w * v.w;
            }
        }
    }
    const int gr = 2 + 4 * rs;
    float tsum = 0.f, msum = 0.f;
#pragma unroll
    for (int u = 0; u < 4; ++u) {
        const int gc = 2 + 4 * (4 * q + u);
        const float m = spec[(long)band * HWSZ + (long)gr * IMG + gc];
        const float y = labels[((long)b * 9 + band) * HWSZ + (long)gr * IMG + gc];
        tsum += fabsf(o[u] * m - y * m);
        msum += m;
    }
    blockReduceAtomicAdd((double)tsum, acc + 0, redT);
    blockReduceAtomicAdd((double)msum, acc + 1, redM);
}

__global__ void k_final(const double* __restrict__ acc, float* __restrict__ out) {
    double lspec = acc[0] / acc[1];
    double lstruct = acc[2] / (double)(NBATCH * NBANDS * HWSZ);
    out[0] = (float)(lspec + 0.25 * lstruct);
}

// ---------------------------------------------------------------------------
extern "C" void kernel_launch(void* const* d_in, const int* in_sizes, int n_in,
                              void* d_out, int out_size, void* d_ws, size_t ws_size,
                              hipStream_t stream) {
    const float* outputs = (const float*)d_in[0];   // (4,8,512,512)
    const float* labels  = (const float*)d_in[1];   // (4,9,512,512)
    const float* inp     = (const float*)d_in[2];   // (4,9,512,512)
    const float* mtf     = (const float*)d_in[3];   // (8,1,41,41)
    const float* spec    = (const float*)d_in[4];   // (1,8,512,512)
    float* out = (float*)d_out;

    const long IMGB = (long)HWSZ;     // one image in elements
    char* ws = (char*)d_ws;
    double* acc    = (double*)ws;                    // 4 doubles
    float* panf    = (float*)(ws + 1024);            // 4 imgs fp32
    float* tmpH    = panf   + NBATCH * IMGB;         // 4 imgs (unused now)
    float* da_pan8 = tmpH   + NBATCH * IMGB;         // 4 imgs
    float* saa8    = da_pan8 + NBATCH * IMGB;        // 4 imgs
    float* db_pan2 = saa8   + NBATCH * IMGB;         // 4 imgs
    float* sbb2    = db_pan2 + NBATCH * IMGB;        // 4 imgs
    float* tmpS    = sbb2   + NBATCH * IMGB;         // 8 imgs fp32
    half_t* hDA8   = (half_t*)(tmpS + 8 * IMGB);     // 32 imgs half: da_ms  (w=8)
    half_t* hDA2   = hDA8 + 32 * IMGB;               // 32 imgs half: da_out (w=2)

    hipMemsetAsync(acc, 0, 4 * sizeof(double), stream);

    // --- per-batch shared fields (fp32) ----------------------------------
    kPan<<<dim3(16, 16, NBATCH), 256, 0, stream>>>(inp, mtf, panf);
    k_da<8><<<dim3(16, 16, NBATCH), 256, 0, stream>>>(panf, (long)HWSZ, da_pan8);
    k_sq<8><<<dim3(16, 16, NBATCH), 256, 0, stream>>>(da_pan8, saa8);
    k_da<2><<<dim3(16, 16, NBATCH), 256, 0, stream>>>(labels + 8 * IMGB,
                                                      (long)9 * HWSZ, db_pan2);
    k_sq<2><<<dim3(16, 16, NBATCH), 256, 0, stream>>>(db_pan2, sbb2);

    // --- da fields (w=8) + fused da/spec-H (w=2) --------------------------
    kDAtile<8><<<2048, 256, 0, stream>>>(inp, 9 * IMGB, IMGB, hDA8);
    kDAspec<<<2048, 256, 0, stream>>>(outputs, mtf, hDA2, tmpS);

    // --- fused products + box + thr + X + Y reduce -------------------------
    kFusedXY<<<2048, 256, 0, stream>>>(hDA8, da_pan8, saa8,
                                       hDA2, db_pan2, sbb2, acc);

    // --- L_spec V pass + reduce (independent of kFusedXY) -----------------
    k_spec_v<<<512, 256, 0, stream>>>(tmpS, labels, spec, mtf, acc);

    k_final<<<1, 1, 0, stream>>>(acc, out);
}

// Round 14
// 277.540 us; speedup vs baseline: 1.1202x; 1.0512x over previous
//
#include <hip/hip_runtime.h>
#include <hip/hip_bf16.h>

// Problem constants
#define HWSZ   262144   // 512*512
#define IMG    512
#define NBATCH 4
#define NBANDS 8

typedef _Float16 half_t;
typedef _Float16 half2v __attribute__((ext_vector_type(2)));
typedef _Float16 half4v __attribute__((ext_vector_type(4)));
typedef _Float16 half8v __attribute__((ext_vector_type(8)));

// ---------------------------------------------------------------------------
// Block-level reduction: wave shuffle + LDS + one double atomic per block.
__device__ __forceinline__ void blockReduceAtomicAdd(double v, double* target,
                                                     double* red) {
    for (int off = 32; off > 0; off >>= 1) v += __shfl_down(v, off, 64);
    const int wave = threadIdx.x >> 6, lane = threadIdx.x & 63;
    if (lane == 0) red[wave] = v;
    __syncthreads();
    if (threadIdx.x == 0) atomicAdd(target, red[0] + red[1] + red[2] + red[3]);
}

// ---------------------------------------------------------------------------
// Pan smoothing (edge-pad 41x41 Gaussian, rank-1 factored), horizontal pass.
// NOTE (R13 lesson): do NOT tile-fuse these two passes — halo recompute of a
// 41-tap FIR costs 2.25x its FMAs; the 4 MB tmpH round-trip is cheaper.
__global__ __launch_bounds__(256) void k_pan_h(const float* __restrict__ inp,
                                               const float* __restrict__ mtf,
                                               float* __restrict__ tmpH) {
    __shared__ float seg[296];
    __shared__ float vrow[41];
    const int tid = threadIdx.x;
    const int b = blockIdx.z, r = blockIdx.y, c0 = blockIdx.x * 256;
    if (tid < 41) vrow[tid] = mtf[20 * 41 + tid] / sqrtf(mtf[20 * 41 + 20]);
    const float* pan = inp + ((long)b * 9 + 8) * HWSZ + (long)r * IMG;
    for (int e = tid; e < 296; e += 256) {
        int c = c0 - 20 + e;
        c = min(max(c, 0), IMG - 1);
        seg[e] = pan[c];
    }
    __syncthreads();
    float s = 0.f;
#pragma unroll
    for (int j = 0; j < 41; ++j) s += vrow[j] * seg[tid + j];
    tmpH[(long)b * HWSZ + (long)r * IMG + c0 + tid] = s;
}

__global__ __launch_bounds__(256) void k_pan_v(const float* __restrict__ tmpH,
                                               const float* __restrict__ mtf,
                                               float* __restrict__ panf) {
    __shared__ float ucol[41];
    const int tid = threadIdx.x;
    const int b = blockIdx.z, r = blockIdx.y, c = blockIdx.x * 256 + tid;
    if (tid < 41) ucol[tid] = mtf[tid * 41 + 20] / sqrtf(mtf[20 * 41 + 20]);
    __syncthreads();
    const float* base = tmpH + (long)b * HWSZ;
    float s = 0.f;
#pragma unroll
    for (int i = 0; i < 41; ++i) {
        int rr = min(max(r - 20 + i, 0), IMG - 1);
        s += ucol[i] * base[(long)rr * IMG + c];
    }
    panf[(long)b * HWSZ + (long)r * IMG + c] = s;
}

// ---------------------------------------------------------------------------
// Small-field (4-image) helpers, LDS tile based (cheap at this size).
template <int W>
__global__ __launch_bounds__(256) void k_da(const float* __restrict__ in,
                                            long inBatchStride,
                                            float* __restrict__ out) {
    constexpr int TS = 32, WIN = 2 * W, NN = 4 * W * W, RE = TS + WIN - 1;
    constexpr int SR = RE;
    constexpr int ST = 33;
    __shared__ float RAW[RE * SR];
    __shared__ float T[RE * ST];
    const int tid = threadIdx.x;
    const int tr0 = blockIdx.y * TS, tc0 = blockIdx.x * TS;
    const float* src = in + (long)blockIdx.z * inBatchStride;
    for (int e = tid; e < RE * RE; e += 256) {
        int r = e / RE, c = e % RE;
        int gr = tr0 - (W - 1) + r, gc = tc0 - (W - 1) + c;
        float v = 0.f;
        if (gr >= 0 && gr < IMG && gc >= 0 && gc < IMG) v = src[(long)gr * IMG + gc];
        RAW[r * SR + c] = v;
    }
    __syncthreads();
    for (int e = tid; e < RE * TS; e += 256) {
        int r = e >> 5, j = e & 31;
        float s = 0.f;
#pragma unroll
        for (int k = 0; k < WIN; ++k) s += RAW[r * SR + j + k];
        T[r * ST + j] = s;
    }
    __syncthreads();
    float* dst = out + (long)blockIdx.z * HWSZ;
    for (int e = tid; e < TS * TS; e += 256) {
        int pr = e >> 5, pc = e & 31;
        float s = 0.f;
#pragma unroll
        for (int k = 0; k < WIN; ++k) s += T[(pr + k) * ST + pc];
        float da = RAW[(pr + W - 1) * SR + (pc + W - 1)] - s * (1.0f / NN);
        dst[(long)(tr0 + pr) * IMG + tc0 + pc] = da;
    }
}

template <int W>
__global__ __launch_bounds__(256) void k_sq(const float* __restrict__ in,
                                            float* __restrict__ out) {
    constexpr int TS = 32, WIN = 2 * W, RE = TS + WIN - 1;
    constexpr int SR = RE, ST = 33;
    __shared__ float RAW[RE * SR];
    __shared__ float T[RE * ST];
    const int tid = threadIdx.x;
    const int tr0 = blockIdx.y * TS, tc0 = blockIdx.x * TS;
    const float* src = in + (long)blockIdx.z * HWSZ;
    for (int e = tid; e < RE * RE; e += 256) {
        int r = e / RE, c = e % RE;
        int gr = tr0 - (W - 1) + r, gc = tc0 - (W - 1) + c;
        float v = 0.f;
        if (gr >= 0 && gr < IMG && gc >= 0 && gc < IMG) v = src[(long)gr * IMG + gc];
        RAW[r * SR + c] = v;
    }
    __syncthreads();
    for (int e = tid; e < RE * TS; e += 256) {
        int r = e >> 5, j = e & 31;
        float s = 0.f;
#pragma unroll
        for (int k = 0; k < WIN; ++k) {
            float v = RAW[r * SR + j + k];
            s += v * v;
        }
        T[r * ST + j] = s;
    }
    __syncthreads();
    float* dst = out + (long)blockIdx.z * HWSZ;
    for (int e = tid; e < TS * TS; e += 256) {
        int pr = e >> 5, pc = e & 31;
        float s = 0.f;
#pragma unroll
        for (int k = 0; k < WIN; ++k) s += T[(pr + k) * ST + pc];
        dst[(long)(tr0 + pr) * IMG + tc0 + pc] = s;
    }
}

// ---------------------------------------------------------------------------
// Sliding-window helpers for the full-size (32-image) path.

template <int W> struct WinDims {
    static constexpr int A  = (W + 3) & ~3;
    static constexpr int NU = A + W + 8;              // elements actually used
    static constexpr int NF = (NU + 3) / 4;           // 4-elem chunks loaded
    static constexpr int NV = NF * 4;                 // padded array size
};

template <int W>
__device__ __forceinline__ void loadRowWin(const float* __restrict__ row, int c0,
                                           float* v) {
    constexpr int A = WinDims<W>::A;
    constexpr int NF = WinDims<W>::NF;
#pragma unroll
    for (int f = 0; f < NF; ++f) {
        const int cb = c0 - A + 4 * f;
        if (cb >= 0 && cb + 3 < IMG) {
            const float4 t = *(const float4*)(row + cb);
            v[4 * f + 0] = t.x; v[4 * f + 1] = t.y;
            v[4 * f + 2] = t.z; v[4 * f + 3] = t.w;
        } else {
#pragma unroll
            for (int u = 0; u < 4; ++u) {
                const int c = cb + u;
                v[4 * f + u] = (c >= 0 && c < IMG) ? row[c] : 0.f;
            }
        }
    }
}

template <int W>
__device__ __forceinline__ void loadRowWinH(const half_t* __restrict__ row, int c0,
                                            float* v) {
    constexpr int A = WinDims<W>::A;
    constexpr int NF = WinDims<W>::NF;
#pragma unroll
    for (int f = 0; f < NF; ++f) {
        const int cb = c0 - A + 4 * f;   // multiple of 4 -> 8B aligned
        if (cb >= 0 && cb + 3 < IMG) {
            const half4v t = *(const half4v*)(row + cb);
            v[4 * f + 0] = (float)t[0]; v[4 * f + 1] = (float)t[1];
            v[4 * f + 2] = (float)t[2]; v[4 * f + 3] = (float)t[3];
        } else {
#pragma unroll
            for (int u = 0; u < 4; ++u) {
                const int c = cb + u;
                v[4 * f + u] = (c >= 0 && c < IMG) ? (float)row[c] : 0.f;
            }
        }
    }
}

// ---------------------------------------------------------------------------
// XCD-aware decode for the full-size tile kernels (2048-block flat grids).
// Same decode in producers (kDAtile/kDAspec) and consumer (kFusedXY) so each
// tile's da slice stays XCD-L2-local across the back-to-back launches.
__device__ __forceinline__ void xcdDecode(int id, int& z, int& tr0, int& tc0) {
    const int xcd = id & 7, inner = id >> 3;
    z = (xcd << 2) | (inner >> 6);
    const int t = inner & 63;
    tr0 = (t >> 3) * 64;
    tc0 = (t & 7) * 64;
}

// ---------------------------------------------------------------------------
// Fused da kernel (H-box + V-box + da epilogue), 64x64 tile, one barrier.
// grid 2048 x 256 (XCD-swizzled). Used for the w=8 (inp ms) pipeline.
template <int W>
__global__ __launch_bounds__(256) void kDAtile(const float* __restrict__ in,
                                               long sB, long sC,
                                               half_t* __restrict__ out) {
    constexpr int A = WinDims<W>::A;
    constexpr int NV = WinDims<W>::NV;
    constexpr int NRS = 63 + 2 * W;               // staged t rows
    constexpr int LP = 65;                        // float pitch
    constexpr int NN = 4 * W * W;
    __shared__ float T[NRS * LP];
    int z, tr0, tc0;
    xcdDecode(blockIdx.x, z, tr0, tc0);
    const float* img = in + (long)(z >> 3) * sB + (long)(z & 7) * sC;

    // phase 1: t = H-box(raw), rows tr0-W+1 .. tr0+62+W, cols tc0..tc0+63
    for (int e = threadIdx.x; e < NRS * 8; e += 256) {
        const int i = e >> 3, cg = e & 7;
        const int gr = tr0 - W + 1 + i;
        float* dst = &T[i * LP + cg * 8];
        if (gr < 0 || gr >= IMG) {
#pragma unroll
            for (int j = 0; j < 8; ++j) dst[j] = 0.f;
            continue;
        }
        float v[NV];
        loadRowWin<W>(img + (long)gr * IMG, tc0 + cg * 8, v);
        float s = 0.f;
#pragma unroll
        for (int k = A - W + 1; k <= A + W; ++k) s += v[k];
        dst[0] = s;
#pragma unroll
        for (int j = 1; j < 8; ++j) {
            s += v[A + W + j] - v[A - W + j];
            dst[j] = s;
        }
    }
    __syncthreads();

    // phase 2: V-slide + epilogue
    const int c = threadIdx.x & 63, q = threadIdx.x >> 6;
    const int ro0 = q * 16;
    float s = 0.f;
#pragma unroll
    for (int k = 0; k < 2 * W; ++k) s += T[(ro0 + k) * LP + c];
    const float* oz = img + tc0 + c;
    half_t* dz = out + (long)z * HWSZ + tc0 + c;
#pragma unroll
    for (int j = 0; j < 16; ++j) {
        const int r = tr0 + ro0 + j;
        const float o = oz[(long)r * IMG];
        dz[(long)r * IMG] = (half_t)(o - s * (1.0f / NN));
        if (j < 15) s += T[(ro0 + j + 2 * W) * LP + c] - T[(ro0 + j) * LP + c];
    }
}

// ---------------------------------------------------------------------------
// kDAspec: kDAtile<2> on `outputs` + the L_spec 41-tap H-conv fused as a
// third phase (replaces k_spec_h). Phase 3 is the k_spec_h register-window
// body (14 float4 loads, 4 accumulators, identical accumulation order).
// grid 2048 x 256 (XCD-swizzled).
__global__ __launch_bounds__(256) void kDAspec(const float* __restrict__ outputs,
                                               const float* __restrict__ mtf,
                                               half_t* __restrict__ outDA,
                                               float* __restrict__ tmpS) {
    constexpr int W = 2;
    constexpr int A = WinDims<W>::A;
    constexpr int NV = WinDims<W>::NV;
    constexpr int NRS = 63 + 2 * W;               // 67
    constexpr int LP = 65;
    constexpr int NN = 4 * W * W;
    __shared__ float T[NRS * LP];
    __shared__ float vrow[41];
    int z, tr0, tc0;
    xcdDecode(blockIdx.x, z, tr0, tc0);
    const int band = z & 7;
    if (threadIdx.x < 41)
        vrow[threadIdx.x] = mtf[band * 1681 + 20 * 41 + threadIdx.x] /
                            sqrtf(mtf[band * 1681 + 20 * 41 + 20]);
    const float* img = outputs + (long)z * HWSZ;

    // phase 1: t = H-box(raw)
    for (int e = threadIdx.x; e < NRS * 8; e += 256) {
        const int i = e >> 3, cg = e & 7;
        const int gr = tr0 - W + 1 + i;
        float* dst = &T[i * LP + cg * 8];
        if (gr < 0 || gr >= IMG) {
#pragma unroll
            for (int j = 0; j < 8; ++j) dst[j] = 0.f;
            continue;
        }
        float v[NV];
        loadRowWin<W>(img + (long)gr * IMG, tc0 + cg * 8, v);
        float s = 0.f;
#pragma unroll
        for (int k = A - W + 1; k <= A + W; ++k) s += v[k];
        dst[0] = s;
#pragma unroll
        for (int j = 1; j < 8; ++j) {
            s += v[A + W + j] - v[A - W + j];
            dst[j] = s;
        }
    }
    __syncthreads();   // also publishes vrow

    // phase 2: V-slide + da epilogue
    const int c = threadIdx.x & 63, q = threadIdx.x >> 6;
    const int ro0 = q * 16;
    float s = 0.f;
#pragma unroll
    for (int k = 0; k < 2 * W; ++k) s += T[(ro0 + k) * LP + c];
    const float* oz = img + tc0 + c;
    half_t* dz = outDA + (long)z * HWSZ + tc0 + c;
#pragma unroll
    for (int j = 0; j < 16; ++j) {
        const int r = tr0 + ro0 + j;
        const float o = oz[(long)r * IMG];
        dz[(long)r * IMG] = (half_t)(o - s * (1.0f / NN));
        if (j < 15) s += T[(ro0 + j + 2 * W) * LP + c] - T[(ro0 + j) * LP + c];
    }

    // phase 3: spec H-conv, k_spec_h register-window body on the tile.
    {
        const int r = threadIdx.x >> 2, u = threadIdx.x & 3;
        const float* row = img + (long)(tr0 + r) * IMG;
        float v[56];
#pragma unroll
        for (int f = 0; f < 14; ++f) {
            const int cb = tc0 + 16 * u - 20 + 4 * f;
            if (cb >= 0 && cb + 3 < IMG) {
                const float4 t = *(const float4*)(row + cb);
                v[4 * f + 0] = t.x; v[4 * f + 1] = t.y;
                v[4 * f + 2] = t.z; v[4 * f + 3] = t.w;
            } else {
#pragma unroll
                for (int uu = 0; uu < 4; ++uu) {
                    const int cc = cb + uu;
                    v[4 * f + uu] = (cc >= 0 && cc < IMG) ? row[cc] : 0.f;
                }
            }
        }
        float o[4] = {0.f, 0.f, 0.f, 0.f};
#pragma unroll
        for (int j = 0; j < 41; ++j) {
            const float w = vrow[j];
#pragma unroll
            for (int uu = 0; uu < 4; ++uu) o[uu] += w * v[2 + 4 * uu + j];
        }
        float* ts = tmpS + ((long)z * IMG + tr0 + r) * 128 + (tc0 >> 2) + 4 * u;
        *(float4*)ts = make_float4(o[0], o[1], o[2], o[3]);
    }
}

// ---------------------------------------------------------------------------
// Fused product + H-box staging: per 64x64 tile, H-box of (da*dshared, da*da)
// rows into LDS as packed half2(p1,p2).
template <int W>
__device__ __forceinline__ void stageProducts(const half_t* __restrict__ daz,
                                              const float* __restrict__ dsz,
                                              int tr0, int tc0,
                                              unsigned int* L) {
    constexpr int A = WinDims<W>::A;
    constexpr int NU = WinDims<W>::NU;
    constexpr int NV = WinDims<W>::NV;
    constexpr int NRS = 63 + 2 * W;               // staged product rows
    constexpr int LP = 65;                        // uint pitch (4B units)
    for (int e = threadIdx.x; e < NRS * 8; e += 256) {
        const int i = e >> 3, cg = e & 7;
        const int gr = tr0 - W + 1 + i;
        const int c0 = tc0 + cg * 8;
        unsigned int* dst = L + i * LP + cg * 8;
        if (gr < 0 || gr >= IMG) {
#pragma unroll
            for (int j = 0; j < 8; ++j) dst[j] = 0u;
            continue;
        }
        float va[NV], vs[NV];
        loadRowWinH<W>(daz + (long)gr * IMG, c0, va);
        loadRowWin<W>(dsz + (long)gr * IMG, c0, vs);
        float p1[NV], p2[NV];
#pragma unroll
        for (int k = 0; k < NU; ++k) { p1[k] = va[k] * vs[k]; p2[k] = va[k] * va[k]; }
        float s1 = 0.f, s2 = 0.f;
#pragma unroll
        for (int k = A - W + 1; k <= A + W; ++k) { s1 += p1[k]; s2 += p2[k]; }
#pragma unroll
        for (int j = 0; j < 8; ++j) {
            half2v h;
            h[0] = (half_t)s1; h[1] = (half_t)s2;
            dst[j] = __builtin_bit_cast(unsigned int, h);
            if (j < 7) {
                s1 += p1[A + W + 1 + j] - p1[A - W + 1 + j];
                s2 += p2[A + W + 1 + j] - p2[A - W + 1 + j];
            }
        }
    }
}

// ---------------------------------------------------------------------------
// Fully fused structural kernel, single-barrier schedule: stage BOTH product
// pipelines (separate LDS buffers) -> one sync -> V8(thr in regs) -> V2(Y).
// LDS 38 KB -> 4 blocks/CU. grid 2048 x 256 (XCD-swizzled).
__global__ __launch_bounds__(256, 4) void kFusedXY(
    const half_t* __restrict__ daMS,
    const float* __restrict__ daPAN,
    const float* __restrict__ saa,
    const half_t* __restrict__ daOUT,
    const float* __restrict__ dbPAN,
    const float* __restrict__ sbb,
    double* __restrict__ acc) {
    constexpr int LP = 65;
    constexpr int NRS8 = 63 + 16;                 // 79 (w=8)
    constexpr int NRS2 = 63 + 4;                  // 67 (w=2)
    __shared__ unsigned int L8[NRS8 * LP];
    __shared__ unsigned int L2b[NRS2 * LP];
    __shared__ double red[4];
    int z, tr0, tc0;
    xcdDecode(blockIdx.x, z, tr0, tc0);
    const int b = z >> 3;
    const int c = threadIdx.x & 63, q = threadIdx.x >> 6;
    const int ro0 = q * 16;

    // ---- stage both pipelines, then one barrier -------------------------
    stageProducts<8>(daMS + (long)z * HWSZ, daPAN + (long)b * HWSZ, tr0, tc0, L8);
    stageProducts<2>(daOUT + (long)z * HWSZ, dbPAN + (long)b * HWSZ, tr0, tc0, L2b);
    __syncthreads();

    float thrv[16];
    {   // ---------------- w = 8: thr ----------------
        constexpr int W = 8;
        float s1 = 0.f, s2 = 0.f;
#pragma unroll
        for (int k = 0; k < 2 * W; ++k) {
            const half2v h = __builtin_bit_cast(half2v, L8[(ro0 + k) * LP + c]);
            s1 += (float)h[0]; s2 += (float)h[1];
        }
        const float* sz = saa + (long)b * HWSZ + tc0 + c;
#pragma unroll
        for (int j = 0; j < 16; ++j) {
            const int r = tr0 + ro0 + j;
            const float sa = sz[(long)r * IMG];
            const float den = sqrtf(fmaxf(sa * s2, 0.f)) + 1e-20f;
            thrv[j] = 1.0f - s1 / den;
            if (j < 15) {
                const half2v ha = __builtin_bit_cast(half2v, L8[(ro0 + j + 2 * W) * LP + c]);
                const half2v hs = __builtin_bit_cast(half2v, L8[(ro0 + j) * LP + c]);
                s1 += (float)ha[0] - (float)hs[0];
                s2 += (float)ha[1] - (float)hs[1];
            }
        }
    }
    double ysum = 0.0;
    {   // ---------------- w = 2: X vs thr, Y ---------- (no barrier needed)
        constexpr int W = 2;
        float s1 = 0.f, s2 = 0.f;
#pragma unroll
        for (int k = 0; k < 2 * W; ++k) {
            const half2v h = __builtin_bit_cast(half2v, L2b[(ro0 + k) * LP + c]);
            s1 += (float)h[0]; s2 += (float)h[1];
        }
        const float* sz = sbb + (long)b * HWSZ + tc0 + c;
#pragma unroll
        for (int j = 0; j < 16; ++j) {
            const float sb = sz[(long)(tr0 + ro0 + j) * IMG];
            const float den = sqrtf(fmaxf(s2 * sb, 0.f)) + 1e-20f;
            const float Xc = s1 / den;
            const float X = 1.0f - fmaxf(Xc, -1.0f);
            if (X > thrv[j]) ysum += (double)X;
            if (j < 15) {
                const half2v ha = __builtin_bit_cast(half2v, L2b[(ro0 + j + 2 * W) * LP + c]);
                const half2v hs = __builtin_bit_cast(half2v, L2b[(ro0 + j) * LP + c]);
                s1 += (float)ha[0] - (float)hs[0];
                s2 += (float)ha[1] - (float)hs[1];
            }
        }
    }
    blockReduceAtomicAdd(ysum, acc + 2, red);
}

// ---------------------------------------------------------------------------
// L_spec V pass + reduce (H pass is fused into kDAspec).
__global__ __launch_bounds__(256) void k_spec_v(const float* __restrict__ tmpS,
                                                const float* __restrict__ labels,
                                                const float* __restrict__ spec,
                                                const float* __restrict__ mtf,
                                                double* __restrict__ acc) {
    __shared__ double redT[4];
    __shared__ double redM[4];
    __shared__ float ucol[41];
    const int g = blockIdx.x * 256 + threadIdx.x;
    const int q = g & 31, rs = (g >> 5) & 127, z = g >> 12;   // z uniform/block
    const int b = z >> 3, band = z & 7;
    if (threadIdx.x < 41)
        ucol[threadIdx.x] = mtf[band * 1681 + threadIdx.x * 41 + 20] /
                            sqrtf(mtf[band * 1681 + 20 * 41 + 20]);
    __syncthreads();
    const float* base = tmpS + (long)z * IMG * 128 + 4 * q;
    const int rbase = 4 * rs - 18;
    float o[4] = {0.f, 0.f, 0.f, 0.f};
    if (rbase >= 0 && rbase + 40 < IMG) {
#pragma unroll
        for (int i = 0; i < 41; ++i) {
            const float4 v = *(const float4*)(base + (long)(rbase + i) * 128);
            const float w = ucol[i];
            o[0] += w * v.x; o[1] += w * v.y; o[2] += w * v.z; o[3] += w * v.w;
        }
    } else {
        for (int i = 0; i < 41; ++i) {
            const int r = rbase + i;
            if (r >= 0 && r < IMG) {
                const float4 v = *(const float4*)(base + (long)r * 128);
                const float w = ucol[i];
                o[0] += w * v.x; o[1] += w * v.y; o[2] += w * v.z; o[3] += w * v.w;
            }
        }
    }
    const int gr = 2 + 4 * rs;
    float tsum = 0.f, msum = 0.f;
#pragma unroll
    for (int u = 0; u < 4; ++u) {
        const int gc = 2 + 4 * (4 * q + u);
        const float m = spec[(long)band * HWSZ + (long)gr * IMG + gc];
        const float y = labels[((long)b * 9 + band) * HWSZ + (long)gr * IMG + gc];
        tsum += fabsf(o[u] * m - y * m);
        msum += m;
    }
    blockReduceAtomicAdd((double)tsum, acc + 0, redT);
    blockReduceAtomicAdd((double)msum, acc + 1, redM);
}

__global__ void k_final(const double* __restrict__ acc, float* __restrict__ out) {
    double lspec = acc[0] / acc[1];
    double lstruct = acc[2] / (double)(NBATCH * NBANDS * HWSZ);
    out[0] = (float)(lspec + 0.25 * lstruct);
}

// ---------------------------------------------------------------------------
extern "C" void kernel_launch(void* const* d_in, const int* in_sizes, int n_in,
                              void* d_out, int out_size, void* d_ws, size_t ws_size,
                              hipStream_t stream) {
    const float* outputs = (const float*)d_in[0];   // (4,8,512,512)
    const float* labels  = (const float*)d_in[1];   // (4,9,512,512)
    const float* inp     = (const float*)d_in[2];   // (4,9,512,512)
    const float* mtf     = (const float*)d_in[3];   // (8,1,41,41)
    const float* spec    = (const float*)d_in[4];   // (1,8,512,512)
    float* out = (float*)d_out;

    const long IMGB = (long)HWSZ;     // one image in elements
    char* ws = (char*)d_ws;
    double* acc    = (double*)ws;                    // 4 doubles
    float* panf    = (float*)(ws + 1024);            // 4 imgs fp32
    float* tmpH    = panf   + NBATCH * IMGB;         // 4 imgs
    float* da_pan8 = tmpH   + NBATCH * IMGB;         // 4 imgs
    float* saa8    = da_pan8 + NBATCH * IMGB;        // 4 imgs
    float* db_pan2 = saa8   + NBATCH * IMGB;         // 4 imgs
    float* sbb2    = db_pan2 + NBATCH * IMGB;        // 4 imgs
    float* tmpS    = sbb2   + NBATCH * IMGB;         // 8 imgs fp32
    half_t* hDA8   = (half_t*)(tmpS + 8 * IMGB);     // 32 imgs half: da_ms  (w=8)
    half_t* hDA2   = hDA8 + 32 * IMGB;               // 32 imgs half: da_out (w=2)

    hipMemsetAsync(acc, 0, 4 * sizeof(double), stream);

    // --- per-batch shared fields (fp32) ----------------------------------
    k_pan_h<<<dim3(2, 512, NBATCH), 256, 0, stream>>>(inp, mtf, tmpH);
    k_pan_v<<<dim3(2, 512, NBATCH), 256, 0, stream>>>(tmpH, mtf, panf);
    k_da<8><<<dim3(16, 16, NBATCH), 256, 0, stream>>>(panf, (long)HWSZ, da_pan8);
    k_sq<8><<<dim3(16, 16, NBATCH), 256, 0, stream>>>(da_pan8, saa8);
    k_da<2><<<dim3(16, 16, NBATCH), 256, 0, stream>>>(labels + 8 * IMGB,
                                                      (long)9 * HWSZ, db_pan2);
    k_sq<2><<<dim3(16, 16, NBATCH), 256, 0, stream>>>(db_pan2, sbb2);

    // --- da fields (w=8) + fused da/spec-H (w=2) --------------------------
    kDAtile<8><<<2048, 256, 0, stream>>>(inp, 9 * IMGB, IMGB, hDA8);
    kDAspec<<<2048, 256, 0, stream>>>(outputs, mtf, hDA2, tmpS);

    // --- fused products + box + thr + X + Y reduce -------------------------
    // Launched IMMEDIATELY after its producers so hDA2 (and part of hDA8)
    // are still XCD-L2-resident (same xcdDecode on producer and consumer).
    kFusedXY<<<2048, 256, 0, stream>>>(hDA8, da_pan8, saa8,
                                       hDA2, db_pan2, sbb2, acc);

    // --- L_spec V pass + reduce (independent of kFusedXY) -----------------
    k_spec_v<<<512, 256, 0, stream>>>(tmpS, labels, spec, mtf, acc);

    k_final<<<1, 1, 0, stream>>>(acc, out);
}

// Round 15
// 269.592 us; speedup vs baseline: 1.1532x; 1.0295x over previous
//
#include <hip/hip_runtime.h>
#include <hip/hip_bf16.h>

// Problem constants
#define HWSZ   262144   // 512*512
#define IMG    512
#define NBATCH 4
#define NBANDS 8

typedef _Float16 half_t;
typedef _Float16 half2v __attribute__((ext_vector_type(2)));
typedef _Float16 half4v __attribute__((ext_vector_type(4)));
typedef _Float16 half8v __attribute__((ext_vector_type(8)));

// ---------------------------------------------------------------------------
// Block-level reduction: wave shuffle + LDS + one double atomic per block.
__device__ __forceinline__ void blockReduceAtomicAdd(double v, double* target,
                                                     double* red) {
    for (int off = 32; off > 0; off >>= 1) v += __shfl_down(v, off, 64);
    const int wave = threadIdx.x >> 6, lane = threadIdx.x & 63;
    if (lane == 0) red[wave] = v;
    __syncthreads();
    if (threadIdx.x == 0) atomicAdd(target, red[0] + red[1] + red[2] + red[3]);
}

// ---------------------------------------------------------------------------
// Pan smoothing (edge-pad 41x41 Gaussian, rank-1 factored), horizontal pass.
// NOTE (R13 lesson): do NOT tile-fuse these two passes — halo recompute of a
// 41-tap FIR costs 2.25x its FMAs; the 4 MB tmpH round-trip is cheaper.
__global__ __launch_bounds__(256) void k_pan_h(const float* __restrict__ inp,
                                               const float* __restrict__ mtf,
                                               float* __restrict__ tmpH) {
    __shared__ float seg[296];
    __shared__ float vrow[41];
    const int tid = threadIdx.x;
    const int b = blockIdx.z, r = blockIdx.y, c0 = blockIdx.x * 256;
    if (tid < 41) vrow[tid] = mtf[20 * 41 + tid] / sqrtf(mtf[20 * 41 + 20]);
    const float* pan = inp + ((long)b * 9 + 8) * HWSZ + (long)r * IMG;
    for (int e = tid; e < 296; e += 256) {
        int c = c0 - 20 + e;
        c = min(max(c, 0), IMG - 1);
        seg[e] = pan[c];
    }
    __syncthreads();
    float s = 0.f;
#pragma unroll
    for (int j = 0; j < 41; ++j) s += vrow[j] * seg[tid + j];
    tmpH[(long)b * HWSZ + (long)r * IMG + c0 + tid] = s;
}

__global__ __launch_bounds__(256) void k_pan_v(const float* __restrict__ tmpH,
                                               const float* __restrict__ mtf,
                                               float* __restrict__ panf) {
    __shared__ float ucol[41];
    const int tid = threadIdx.x;
    const int b = blockIdx.z, r = blockIdx.y, c = blockIdx.x * 256 + tid;
    if (tid < 41) ucol[tid] = mtf[tid * 41 + 20] / sqrtf(mtf[20 * 41 + 20]);
    __syncthreads();
    const float* base = tmpH + (long)b * HWSZ;
    float s = 0.f;
#pragma unroll
    for (int i = 0; i < 41; ++i) {
        int rr = min(max(r - 20 + i, 0), IMG - 1);
        s += ucol[i] * base[(long)rr * IMG + c];
    }
    panf[(long)b * HWSZ + (long)r * IMG + c] = s;
}

// ---------------------------------------------------------------------------
// Small-field (4-image) tile bodies (verbatim k_da / k_sq math, LDS passed
// in so independent instantiations can share one dispatch).
template <int W>
__device__ __forceinline__ void daTileBody(const float* __restrict__ src,
                                           float* __restrict__ dst,
                                           int tr0, int tc0,
                                           float* RAW, float* T) {
    constexpr int TS = 32, WIN = 2 * W, NN = 4 * W * W, RE = TS + WIN - 1;
    constexpr int SR = RE, ST = 33;
    const int tid = threadIdx.x;
    for (int e = tid; e < RE * RE; e += 256) {
        int r = e / RE, c = e % RE;
        int gr = tr0 - (W - 1) + r, gc = tc0 - (W - 1) + c;
        float v = 0.f;
        if (gr >= 0 && gr < IMG && gc >= 0 && gc < IMG) v = src[(long)gr * IMG + gc];
        RAW[r * SR + c] = v;
    }
    __syncthreads();
    for (int e = tid; e < RE * TS; e += 256) {
        int r = e >> 5, j = e & 31;
        float s = 0.f;
#pragma unroll
        for (int k = 0; k < WIN; ++k) s += RAW[r * SR + j + k];
        T[r * ST + j] = s;
    }
    __syncthreads();
    for (int e = tid; e < TS * TS; e += 256) {
        int pr = e >> 5, pc = e & 31;
        float s = 0.f;
#pragma unroll
        for (int k = 0; k < WIN; ++k) s += T[(pr + k) * ST + pc];
        float da = RAW[(pr + W - 1) * SR + (pc + W - 1)] - s * (1.0f / NN);
        dst[(long)(tr0 + pr) * IMG + tc0 + pc] = da;
    }
}

template <int W>
__device__ __forceinline__ void sqTileBody(const float* __restrict__ src,
                                           float* __restrict__ dst,
                                           int tr0, int tc0,
                                           float* RAW, float* T) {
    constexpr int TS = 32, WIN = 2 * W, RE = TS + WIN - 1;
    constexpr int SR = RE, ST = 33;
    const int tid = threadIdx.x;
    for (int e = tid; e < RE * RE; e += 256) {
        int r = e / RE, c = e % RE;
        int gr = tr0 - (W - 1) + r, gc = tc0 - (W - 1) + c;
        float v = 0.f;
        if (gr >= 0 && gr < IMG && gc >= 0 && gc < IMG) v = src[(long)gr * IMG + gc];
        RAW[r * SR + c] = v;
    }
    __syncthreads();
    for (int e = tid; e < RE * TS; e += 256) {
        int r = e >> 5, j = e & 31;
        float s = 0.f;
#pragma unroll
        for (int k = 0; k < WIN; ++k) {
            float v = RAW[r * SR + j + k];
            s += v * v;
        }
        T[r * ST + j] = s;
    }
    __syncthreads();
    for (int e = tid; e < TS * TS; e += 256) {
        int pr = e >> 5, pc = e & 31;
        float s = 0.f;
#pragma unroll
        for (int k = 0; k < WIN; ++k) s += T[(pr + k) * ST + pc];
        dst[(long)(tr0 + pr) * IMG + tc0 + pc] = s;
    }
}

// Grid-concat of k_da<8> (panf) and k_da<2> (label pan): one dispatch,
// block-uniform branch on z. LDS sized for the W=8 instantiation; per-block
// math byte-identical to the separate kernels. grid (16,16,8) x 256.
__global__ __launch_bounds__(256) void kDAduo(const float* __restrict__ panf,
                                              const float* __restrict__ labels,
                                              float* __restrict__ da_pan8,
                                              float* __restrict__ db_pan2) {
    __shared__ float RAW[47 * 47];
    __shared__ float T[47 * 33];
    const int tr0 = blockIdx.y * 32, tc0 = blockIdx.x * 32;
    const int zz = blockIdx.z;
    if (zz < 4) {
        daTileBody<8>(panf + (long)zz * HWSZ, da_pan8 + (long)zz * HWSZ,
                      tr0, tc0, RAW, T);
    } else {
        const int b = zz - 4;
        daTileBody<2>(labels + ((long)b * 9 + 8) * HWSZ,
                      db_pan2 + (long)b * HWSZ, tr0, tc0, RAW, T);
    }
}

// Grid-concat of k_sq<8> (da_pan8) and k_sq<2> (db_pan2). grid (16,16,8).
__global__ __launch_bounds__(256) void kSQduo(const float* __restrict__ da_pan8,
                                              const float* __restrict__ db_pan2,
                                              float* __restrict__ saa8,
                                              float* __restrict__ sbb2) {
    __shared__ float RAW[47 * 47];
    __shared__ float T[47 * 33];
    const int tr0 = blockIdx.y * 32, tc0 = blockIdx.x * 32;
    const int zz = blockIdx.z;
    if (zz < 4) {
        sqTileBody<8>(da_pan8 + (long)zz * HWSZ, saa8 + (long)zz * HWSZ,
                      tr0, tc0, RAW, T);
    } else {
        const int b = zz - 4;
        sqTileBody<2>(db_pan2 + (long)b * HWSZ, sbb2 + (long)b * HWSZ,
                      tr0, tc0, RAW, T);
    }
}

// ---------------------------------------------------------------------------
// Sliding-window helpers for the full-size (32-image) path.

template <int W> struct WinDims {
    static constexpr int A  = (W + 3) & ~3;
    static constexpr int NU = A + W + 8;              // elements actually used
    static constexpr int NF = (NU + 3) / 4;           // 4-elem chunks loaded
    static constexpr int NV = NF * 4;                 // padded array size
};

template <int W>
__device__ __forceinline__ void loadRowWin(const float* __restrict__ row, int c0,
                                           float* v) {
    constexpr int A = WinDims<W>::A;
    constexpr int NF = WinDims<W>::NF;
#pragma unroll
    for (int f = 0; f < NF; ++f) {
        const int cb = c0 - A + 4 * f;
        if (cb >= 0 && cb + 3 < IMG) {
            const float4 t = *(const float4*)(row + cb);
            v[4 * f + 0] = t.x; v[4 * f + 1] = t.y;
            v[4 * f + 2] = t.z; v[4 * f + 3] = t.w;
        } else {
#pragma unroll
            for (int u = 0; u < 4; ++u) {
                const int c = cb + u;
                v[4 * f + u] = (c >= 0 && c < IMG) ? row[c] : 0.f;
            }
        }
    }
}

template <int W>
__device__ __forceinline__ void loadRowWinH(const half_t* __restrict__ row, int c0,
                                            float* v) {
    constexpr int A = WinDims<W>::A;
    constexpr int NF = WinDims<W>::NF;
#pragma unroll
    for (int f = 0; f < NF; ++f) {
        const int cb = c0 - A + 4 * f;   // multiple of 4 -> 8B aligned
        if (cb >= 0 && cb + 3 < IMG) {
            const half4v t = *(const half4v*)(row + cb);
            v[4 * f + 0] = (float)t[0]; v[4 * f + 1] = (float)t[1];
            v[4 * f + 2] = (float)t[2]; v[4 * f + 3] = (float)t[3];
        } else {
#pragma unroll
            for (int u = 0; u < 4; ++u) {
                const int c = cb + u;
                v[4 * f + u] = (c >= 0 && c < IMG) ? (float)row[c] : 0.f;
            }
        }
    }
}

// ---------------------------------------------------------------------------
// XCD-aware decode for the full-size tile kernels (2048-block flat grids).
// Same decode in producers (kDApair halves) and consumer (kFusedXY) so each
// tile's da slice stays XCD-L2-local across the back-to-back launches.
__device__ __forceinline__ void xcdDecode(int id, int& z, int& tr0, int& tc0) {
    const int xcd = id & 7, inner = id >> 3;
    z = (xcd << 2) | (inner >> 6);
    const int t = inner & 63;
    tr0 = (t >> 3) * 64;
    tc0 = (t & 7) * 64;
}

// ---------------------------------------------------------------------------
// kDApair: grid-concat of kDAtile<8>(inp ms) and kDAspec(outputs). Blocks
// 0..2047 run the w=8 da tile; 2048..4095 run the w=2 da tile + spec H-conv.
// 2048 % 8 == 0 so each half's XCD decode is identical to the separate
// kernels. Bodies byte-identical to the round-14 kernels; LDS is one shared
// buffer sized for the larger half (79*65 floats = 20.5 KB).
// grid 4096 x 256.
__global__ __launch_bounds__(256) void kDApair(const float* __restrict__ inp,
                                               const float* __restrict__ outputs,
                                               const float* __restrict__ mtf,
                                               half_t* __restrict__ hDA8,
                                               half_t* __restrict__ hDA2,
                                               float* __restrict__ tmpS) {
    constexpr int LP = 65;
    __shared__ float BUF[79 * LP];                // 20540 B, max of both halves
    const int half = blockIdx.x >> 11;
    int z, tr0, tc0;
    xcdDecode(blockIdx.x & 2047, z, tr0, tc0);
    const int c = threadIdx.x & 63, q = threadIdx.x >> 6;
    const int ro0 = q * 16;

    if (half == 0) {
        // ---------------- kDAtile<8> body (inp ms bands) -----------------
        constexpr int W = 8;
        constexpr int A = WinDims<W>::A;
        constexpr int NV = WinDims<W>::NV;
        constexpr int NRS = 63 + 2 * W;           // 79
        constexpr int NN = 4 * W * W;
        float* T = BUF;
        const float* img = inp + ((long)(z >> 3) * 9 + (z & 7)) * HWSZ;

        for (int e = threadIdx.x; e < NRS * 8; e += 256) {
            const int i = e >> 3, cg = e & 7;
            const int gr = tr0 - W + 1 + i;
            float* dst = &T[i * LP + cg * 8];
            if (gr < 0 || gr >= IMG) {
#pragma unroll
                for (int j = 0; j < 8; ++j) dst[j] = 0.f;
                continue;
            }
            float v[NV];
            loadRowWin<W>(img + (long)gr * IMG, tc0 + cg * 8, v);
            float s = 0.f;
#pragma unroll
            for (int k = A - W + 1; k <= A + W; ++k) s += v[k];
            dst[0] = s;
#pragma unroll
            for (int j = 1; j < 8; ++j) {
                s += v[A + W + j] - v[A - W + j];
                dst[j] = s;
            }
        }
        __syncthreads();

        float s = 0.f;
#pragma unroll
        for (int k = 0; k < 2 * W; ++k) s += T[(ro0 + k) * LP + c];
        const float* oz = img + tc0 + c;
        half_t* dz = hDA8 + (long)z * HWSZ + tc0 + c;
#pragma unroll
        for (int j = 0; j < 16; ++j) {
            const int r = tr0 + ro0 + j;
            const float o = oz[(long)r * IMG];
            dz[(long)r * IMG] = (half_t)(o - s * (1.0f / NN));
            if (j < 15) s += T[(ro0 + j + 2 * W) * LP + c] - T[(ro0 + j) * LP + c];
        }
    } else {
        // ---------------- kDAspec body (outputs) -------------------------
        constexpr int W = 2;
        constexpr int A = WinDims<W>::A;
        constexpr int NV = WinDims<W>::NV;
        constexpr int NRS = 63 + 2 * W;           // 67
        constexpr int NN = 4 * W * W;
        float* T = BUF;                           // 67*65 floats
        float* vrow = BUF + 67 * LP;              // 41 floats, past T
        const int band = z & 7;
        if (threadIdx.x < 41)
            vrow[threadIdx.x] = mtf[band * 1681 + 20 * 41 + threadIdx.x] /
                                sqrtf(mtf[band * 1681 + 20 * 41 + 20]);
        const float* img = outputs + (long)z * HWSZ;

        // phase 1: t = H-box(raw)
        for (int e = threadIdx.x; e < NRS * 8; e += 256) {
            const int i = e >> 3, cg = e & 7;
            const int gr = tr0 - W + 1 + i;
            float* dst = &T[i * LP + cg * 8];
            if (gr < 0 || gr >= IMG) {
#pragma unroll
                for (int j = 0; j < 8; ++j) dst[j] = 0.f;
                continue;
            }
            float v[NV];
            loadRowWin<W>(img + (long)gr * IMG, tc0 + cg * 8, v);
            float s = 0.f;
#pragma unroll
            for (int k = A - W + 1; k <= A + W; ++k) s += v[k];
            dst[0] = s;
#pragma unroll
            for (int j = 1; j < 8; ++j) {
                s += v[A + W + j] - v[A - W + j];
                dst[j] = s;
            }
        }
        __syncthreads();   // also publishes vrow

        // phase 2: V-slide + da epilogue
        float s = 0.f;
#pragma unroll
        for (int k = 0; k < 2 * W; ++k) s += T[(ro0 + k) * LP + c];
        const float* oz = img + tc0 + c;
        half_t* dz = hDA2 + (long)z * HWSZ + tc0 + c;
#pragma unroll
        for (int j = 0; j < 16; ++j) {
            const int r = tr0 + ro0 + j;
            const float o = oz[(long)r * IMG];
            dz[(long)r * IMG] = (half_t)(o - s * (1.0f / NN));
            if (j < 15) s += T[(ro0 + j + 2 * W) * LP + c] - T[(ro0 + j) * LP + c];
        }

        // phase 3: spec H-conv, k_spec_h register-window body on the tile.
        {
            const int r = threadIdx.x >> 2, u = threadIdx.x & 3;
            const float* row = img + (long)(tr0 + r) * IMG;
            float v[56];
#pragma unroll
            for (int f = 0; f < 14; ++f) {
                const int cb = tc0 + 16 * u - 20 + 4 * f;
                if (cb >= 0 && cb + 3 < IMG) {
                    const float4 t = *(const float4*)(row + cb);
                    v[4 * f + 0] = t.x; v[4 * f + 1] = t.y;
                    v[4 * f + 2] = t.z; v[4 * f + 3] = t.w;
                } else {
#pragma unroll
                    for (int uu = 0; uu < 4; ++uu) {
                        const int cc = cb + uu;
                        v[4 * f + uu] = (cc >= 0 && cc < IMG) ? row[cc] : 0.f;
                    }
                }
            }
            float o[4] = {0.f, 0.f, 0.f, 0.f};
#pragma unroll
            for (int j = 0; j < 41; ++j) {
                const float w = vrow[j];
#pragma unroll
                for (int uu = 0; uu < 4; ++uu) o[uu] += w * v[2 + 4 * uu + j];
            }
            float* ts = tmpS + ((long)z * IMG + tr0 + r) * 128 + (tc0 >> 2) + 4 * u;
            *(float4*)ts = make_float4(o[0], o[1], o[2], o[3]);
        }
    }
}

// ---------------------------------------------------------------------------
// Fused product + H-box staging: per 64x64 tile, H-box of (da*dshared, da*da)
// rows into LDS as packed half2(p1,p2).
template <int W>
__device__ __forceinline__ void stageProducts(const half_t* __restrict__ daz,
                                              const float* __restrict__ dsz,
                                              int tr0, int tc0,
                                              unsigned int* L) {
    constexpr int A = WinDims<W>::A;
    constexpr int NU = WinDims<W>::NU;
    constexpr int NV = WinDims<W>::NV;
    constexpr int NRS = 63 + 2 * W;               // staged product rows
    constexpr int LP = 65;                        // uint pitch (4B units)
    for (int e = threadIdx.x; e < NRS * 8; e += 256) {
        const int i = e >> 3, cg = e & 7;
        const int gr = tr0 - W + 1 + i;
        const int c0 = tc0 + cg * 8;
        unsigned int* dst = L + i * LP + cg * 8;
        if (gr < 0 || gr >= IMG) {
#pragma unroll
            for (int j = 0; j < 8; ++j) dst[j] = 0u;
            continue;
        }
        float va[NV], vs[NV];
        loadRowWinH<W>(daz + (long)gr * IMG, c0, va);
        loadRowWin<W>(dsz + (long)gr * IMG, c0, vs);
        float p1[NV], p2[NV];
#pragma unroll
        for (int k = 0; k < NU; ++k) { p1[k] = va[k] * vs[k]; p2[k] = va[k] * va[k]; }
        float s1 = 0.f, s2 = 0.f;
#pragma unroll
        for (int k = A - W + 1; k <= A + W; ++k) { s1 += p1[k]; s2 += p2[k]; }
#pragma unroll
        for (int j = 0; j < 8; ++j) {
            half2v h;
            h[0] = (half_t)s1; h[1] = (half_t)s2;
            dst[j] = __builtin_bit_cast(unsigned int, h);
            if (j < 7) {
                s1 += p1[A + W + 1 + j] - p1[A - W + 1 + j];
                s2 += p2[A + W + 1 + j] - p2[A - W + 1 + j];
            }
        }
    }
}

// ---------------------------------------------------------------------------
// Fully fused structural kernel, single-barrier schedule: stage BOTH product
// pipelines (separate LDS buffers) -> one sync -> V8(thr in regs) -> V2(Y).
// LDS 38 KB -> 4 blocks/CU. grid 2048 x 256 (XCD-swizzled).
__global__ __launch_bounds__(256, 4) void kFusedXY(
    const half_t* __restrict__ daMS,
    const float* __restrict__ daPAN,
    const float* __restrict__ saa,
    const half_t* __restrict__ daOUT,
    const float* __restrict__ dbPAN,
    const float* __restrict__ sbb,
    double* __restrict__ acc) {
    constexpr int LP = 65;
    constexpr int NRS8 = 63 + 16;                 // 79 (w=8)
    constexpr int NRS2 = 63 + 4;                  // 67 (w=2)
    __shared__ unsigned int L8[NRS8 * LP];
    __shared__ unsigned int L2b[NRS2 * LP];
    __shared__ double red[4];
    int z, tr0, tc0;
    xcdDecode(blockIdx.x, z, tr0, tc0);
    const int b = z >> 3;
    const int c = threadIdx.x & 63, q = threadIdx.x >> 6;
    const int ro0 = q * 16;

    // ---- stage both pipelines, then one barrier -------------------------
    stageProducts<8>(daMS + (long)z * HWSZ, daPAN + (long)b * HWSZ, tr0, tc0, L8);
    stageProducts<2>(daOUT + (long)z * HWSZ, dbPAN + (long)b * HWSZ, tr0, tc0, L2b);
    __syncthreads();

    float thrv[16];
    {   // ---------------- w = 8: thr ----------------
        constexpr int W = 8;
        float s1 = 0.f, s2 = 0.f;
#pragma unroll
        for (int k = 0; k < 2 * W; ++k) {
            const half2v h = __builtin_bit_cast(half2v, L8[(ro0 + k) * LP + c]);
            s1 += (float)h[0]; s2 += (float)h[1];
        }
        const float* sz = saa + (long)b * HWSZ + tc0 + c;
#pragma unroll
        for (int j = 0; j < 16; ++j) {
            const int r = tr0 + ro0 + j;
            const float sa = sz[(long)r * IMG];
            const float den = sqrtf(fmaxf(sa * s2, 0.f)) + 1e-20f;
            thrv[j] = 1.0f - s1 / den;
            if (j < 15) {
                const half2v ha = __builtin_bit_cast(half2v, L8[(ro0 + j + 2 * W) * LP + c]);
                const half2v hs = __builtin_bit_cast(half2v, L8[(ro0 + j) * LP + c]);
                s1 += (float)ha[0] - (float)hs[0];
                s2 += (float)ha[1] - (float)hs[1];
            }
        }
    }
    double ysum = 0.0;
    {   // ---------------- w = 2: X vs thr, Y ---------- (no barrier needed)
        constexpr int W = 2;
        float s1 = 0.f, s2 = 0.f;
#pragma unroll
        for (int k = 0; k < 2 * W; ++k) {
            const half2v h = __builtin_bit_cast(half2v, L2b[(ro0 + k) * LP + c]);
            s1 += (float)h[0]; s2 += (float)h[1];
        }
        const float* sz = sbb + (long)b * HWSZ + tc0 + c;
#pragma unroll
        for (int j = 0; j < 16; ++j) {
            const float sb = sz[(long)(tr0 + ro0 + j) * IMG];
            const float den = sqrtf(fmaxf(s2 * sb, 0.f)) + 1e-20f;
            const float Xc = s1 / den;
            const float X = 1.0f - fmaxf(Xc, -1.0f);
            if (X > thrv[j]) ysum += (double)X;
            if (j < 15) {
                const half2v ha = __builtin_bit_cast(half2v, L2b[(ro0 + j + 2 * W) * LP + c]);
                const half2v hs = __builtin_bit_cast(half2v, L2b[(ro0 + j) * LP + c]);
                s1 += (float)ha[0] - (float)hs[0];
                s2 += (float)ha[1] - (float)hs[1];
            }
        }
    }
    blockReduceAtomicAdd(ysum, acc + 2, red);
}

// ---------------------------------------------------------------------------
// L_spec V pass + reduce (H pass is fused into kDApair's spec half).
__global__ __launch_bounds__(256) void k_spec_v(const float* __restrict__ tmpS,
                                                const float* __restrict__ labels,
                                                const float* __restrict__ spec,
                                                const float* __restrict__ mtf,
                                                double* __restrict__ acc) {
    __shared__ double redT[4];
    __shared__ double redM[4];
    __shared__ float ucol[41];
    const int g = blockIdx.x * 256 + threadIdx.x;
    const int q = g & 31, rs = (g >> 5) & 127, z = g >> 12;   // z uniform/block
    const int b = z >> 3, band = z & 7;
    if (threadIdx.x < 41)
        ucol[threadIdx.x] = mtf[band * 1681 + threadIdx.x * 41 + 20] /
                            sqrtf(mtf[band * 1681 + 20 * 41 + 20]);
    __syncthreads();
    const float* base = tmpS + (long)z * IMG * 128 + 4 * q;
    const int rbase = 4 * rs - 18;
    float o[4] = {0.f, 0.f, 0.f, 0.f};
    if (rbase >= 0 && rbase + 40 < IMG) {
#pragma unroll
        for (int i = 0; i < 41; ++i) {
            const float4 v = *(const float4*)(base + (long)(rbase + i) * 128);
            const float w = ucol[i];
            o[0] += w * v.x; o[1] += w * v.y; o[2] += w * v.z; o[3] += w * v.w;
        }
    } else {
        for (int i = 0; i < 41; ++i) {
            const int r = rbase + i;
            if (r >= 0 && r < IMG) {
                const float4 v = *(const float4*)(base + (long)r * 128);
                const float w = ucol[i];
                o[0] += w * v.x; o[1] += w * v.y; o[2] += w * v.z; o[3] += w * v.w;
            }
        }
    }
    const int gr = 2 + 4 * rs;
    float tsum = 0.f, msum = 0.f;
#pragma unroll
    for (int u = 0; u < 4; ++u) {
        const int gc = 2 + 4 * (4 * q + u);
        const float m = spec[(long)band * HWSZ + (long)gr * IMG + gc];
        const float y = labels[((long)b * 9 + band) * HWSZ + (long)gr * IMG + gc];
        tsum += fabsf(o[u] * m - y * m);
        msum += m;
    }
    blockReduceAtomicAdd((double)tsum, acc + 0, redT);
    blockReduceAtomicAdd((double)msum, acc + 1, redM);
}

__global__ void k_final(const double* __restrict__ acc, float* __restrict__ out) {
    double lspec = acc[0] / acc[1];
    double lstruct = acc[2] / (double)(NBATCH * NBANDS * HWSZ);
    out[0] = (float)(lspec + 0.25 * lstruct);
}

// ---------------------------------------------------------------------------
extern "C" void kernel_launch(void* const* d_in, const int* in_sizes, int n_in,
                              void* d_out, int out_size, void* d_ws, size_t ws_size,
                              hipStream_t stream) {
    const float* outputs = (const float*)d_in[0];   // (4,8,512,512)
    const float* labels  = (const float*)d_in[1];   // (4,9,512,512)
    const float* inp     = (const float*)d_in[2];   // (4,9,512,512)
    const float* mtf     = (const float*)d_in[3];   // (8,1,41,41)
    const float* spec    = (const float*)d_in[4];   // (1,8,512,512)
    float* out = (float*)d_out;

    const long IMGB = (long)HWSZ;     // one image in elements
    char* ws = (char*)d_ws;
    double* acc    = (double*)ws;                    // 4 doubles
    float* panf    = (float*)(ws + 1024);            // 4 imgs fp32
    float* tmpH    = panf   + NBATCH * IMGB;         // 4 imgs
    float* da_pan8 = tmpH   + NBATCH * IMGB;         // 4 imgs
    float* saa8    = da_pan8 + NBATCH * IMGB;        // 4 imgs
    float* db_pan2 = saa8   + NBATCH * IMGB;         // 4 imgs
    float* sbb2    = db_pan2 + NBATCH * IMGB;        // 4 imgs
    float* tmpS    = sbb2   + NBATCH * IMGB;         // 8 imgs fp32
    half_t* hDA8   = (half_t*)(tmpS + 8 * IMGB);     // 32 imgs half: da_ms  (w=8)
    half_t* hDA2   = hDA8 + 32 * IMGB;               // 32 imgs half: da_out (w=2)

    hipMemsetAsync(acc, 0, 4 * sizeof(double), stream);

    // --- per-batch shared fields (fp32) ----------------------------------
    k_pan_h<<<dim3(2, 512, NBATCH), 256, 0, stream>>>(inp, mtf, tmpH);
    k_pan_v<<<dim3(2, 512, NBATCH), 256, 0, stream>>>(tmpH, mtf, panf);
    kDAduo<<<dim3(16, 16, 8), 256, 0, stream>>>(panf, labels, da_pan8, db_pan2);
    kSQduo<<<dim3(16, 16, 8), 256, 0, stream>>>(da_pan8, db_pan2, saa8, sbb2);

    // --- da fields (w=8) + fused da/spec-H (w=2), one dispatch -----------
    kDApair<<<4096, 256, 0, stream>>>(inp, outputs, mtf, hDA8, hDA2, tmpS);

    // --- fused products + box + thr + X + Y reduce -------------------------
    kFusedXY<<<2048, 256, 0, stream>>>(hDA8, da_pan8, saa8,
                                       hDA2, db_pan2, sbb2, acc);

    // --- L_spec V pass + reduce (independent of kFusedXY) -----------------
    k_spec_v<<<512, 256, 0, stream>>>(tmpS, labels, spec, mtf, acc);

    k_final<<<1, 1, 0, stream>>>(acc, out);
}

// Round 16
// 268.072 us; speedup vs baseline: 1.1597x; 1.0057x over previous
//
#include <hip/hip_runtime.h>
#include <hip/hip_bf16.h>

// Problem constants
#define HWSZ   262144   // 512*512
#define IMG    512
#define NBATCH 4
#define NBANDS 8

typedef _Float16 half_t;
typedef _Float16 half2v __attribute__((ext_vector_type(2)));
typedef _Float16 half4v __attribute__((ext_vector_type(4)));
typedef _Float16 half8v __attribute__((ext_vector_type(8)));

// ---------------------------------------------------------------------------
// Block-level reduction: wave shuffle + LDS + one double atomic per block.
__device__ __forceinline__ void blockReduceAtomicAdd(double v, double* target,
                                                     double* red) {
    for (int off = 32; off > 0; off >>= 1) v += __shfl_down(v, off, 64);
    const int wave = threadIdx.x >> 6, lane = threadIdx.x & 63;
    if (lane == 0) red[wave] = v;
    __syncthreads();
    if (threadIdx.x == 0) atomicAdd(target, red[0] + red[1] + red[2] + red[3]);
}

// ---------------------------------------------------------------------------
// Pan smoothing (edge-pad 41x41 Gaussian, rank-1 factored), horizontal pass.
// NOTE (R13 lesson): do NOT tile-fuse these two passes — halo recompute of a
// 41-tap FIR costs 2.25x its FMAs; the 4 MB tmpH round-trip is cheaper.
__global__ __launch_bounds__(256) void k_pan_h(const float* __restrict__ inp,
                                               const float* __restrict__ mtf,
                                               float* __restrict__ tmpH) {
    __shared__ float seg[296];
    __shared__ float vrow[41];
    const int tid = threadIdx.x;
    const int b = blockIdx.z, r = blockIdx.y, c0 = blockIdx.x * 256;
    if (tid < 41) vrow[tid] = mtf[20 * 41 + tid] / sqrtf(mtf[20 * 41 + 20]);
    const float* pan = inp + ((long)b * 9 + 8) * HWSZ + (long)r * IMG;
    for (int e = tid; e < 296; e += 256) {
        int c = c0 - 20 + e;
        c = min(max(c, 0), IMG - 1);
        seg[e] = pan[c];
    }
    __syncthreads();
    float s = 0.f;
#pragma unroll
    for (int j = 0; j < 41; ++j) s += vrow[j] * seg[tid + j];
    tmpH[(long)b * HWSZ + (long)r * IMG + c0 + tid] = s;
}

__global__ __launch_bounds__(256) void k_pan_v(const float* __restrict__ tmpH,
                                               const float* __restrict__ mtf,
                                               float* __restrict__ panf) {
    __shared__ float ucol[41];
    const int tid = threadIdx.x;
    const int b = blockIdx.z, r = blockIdx.y, c = blockIdx.x * 256 + tid;
    if (tid < 41) ucol[tid] = mtf[tid * 41 + 20] / sqrtf(mtf[20 * 41 + 20]);
    __syncthreads();
    const float* base = tmpH + (long)b * HWSZ;
    float s = 0.f;
#pragma unroll
    for (int i = 0; i < 41; ++i) {
        int rr = min(max(r - 20 + i, 0), IMG - 1);
        s += ucol[i] * base[(long)rr * IMG + c];
    }
    panf[(long)b * HWSZ + (long)r * IMG + c] = s;
}

// ---------------------------------------------------------------------------
// Small-field (4-image) tile bodies (verbatim k_da / k_sq math, LDS passed
// in so independent instantiations can share one dispatch).
template <int W>
__device__ __forceinline__ void daTileBody(const float* __restrict__ src,
                                           float* __restrict__ dst,
                                           int tr0, int tc0,
                                           float* RAW, float* T) {
    constexpr int TS = 32, WIN = 2 * W, NN = 4 * W * W, RE = TS + WIN - 1;
    constexpr int SR = RE, ST = 33;
    const int tid = threadIdx.x;
    for (int e = tid; e < RE * RE; e += 256) {
        int r = e / RE, c = e % RE;
        int gr = tr0 - (W - 1) + r, gc = tc0 - (W - 1) + c;
        float v = 0.f;
        if (gr >= 0 && gr < IMG && gc >= 0 && gc < IMG) v = src[(long)gr * IMG + gc];
        RAW[r * SR + c] = v;
    }
    __syncthreads();
    for (int e = tid; e < RE * TS; e += 256) {
        int r = e >> 5, j = e & 31;
        float s = 0.f;
#pragma unroll
        for (int k = 0; k < WIN; ++k) s += RAW[r * SR + j + k];
        T[r * ST + j] = s;
    }
    __syncthreads();
    for (int e = tid; e < TS * TS; e += 256) {
        int pr = e >> 5, pc = e & 31;
        float s = 0.f;
#pragma unroll
        for (int k = 0; k < WIN; ++k) s += T[(pr + k) * ST + pc];
        float da = RAW[(pr + W - 1) * SR + (pc + W - 1)] - s * (1.0f / NN);
        dst[(long)(tr0 + pr) * IMG + tc0 + pc] = da;
    }
}

template <int W>
__device__ __forceinline__ void sqTileBody(const float* __restrict__ src,
                                           float* __restrict__ dst,
                                           int tr0, int tc0,
                                           float* RAW, float* T) {
    constexpr int TS = 32, WIN = 2 * W, RE = TS + WIN - 1;
    constexpr int SR = RE, ST = 33;
    const int tid = threadIdx.x;
    for (int e = tid; e < RE * RE; e += 256) {
        int r = e / RE, c = e % RE;
        int gr = tr0 - (W - 1) + r, gc = tc0 - (W - 1) + c;
        float v = 0.f;
        if (gr >= 0 && gr < IMG && gc >= 0 && gc < IMG) v = src[(long)gr * IMG + gc];
        RAW[r * SR + c] = v;
    }
    __syncthreads();
    for (int e = tid; e < RE * TS; e += 256) {
        int r = e >> 5, j = e & 31;
        float s = 0.f;
#pragma unroll
        for (int k = 0; k < WIN; ++k) {
            float v = RAW[r * SR + j + k];
            s += v * v;
        }
        T[r * ST + j] = s;
    }
    __syncthreads();
    for (int e = tid; e < TS * TS; e += 256) {
        int pr = e >> 5, pc = e & 31;
        float s = 0.f;
#pragma unroll
        for (int k = 0; k < WIN; ++k) s += T[(pr + k) * ST + pc];
        dst[(long)(tr0 + pr) * IMG + tc0 + pc] = s;
    }
}

// Grid-concat of k_da<8> (panf) and k_da<2> (label pan): one dispatch,
// block-uniform branch on z. grid (16,16,8) x 256.
__global__ __launch_bounds__(256) void kDAduo(const float* __restrict__ panf,
                                              const float* __restrict__ labels,
                                              float* __restrict__ da_pan8,
                                              float* __restrict__ db_pan2) {
    __shared__ float RAW[47 * 47];
    __shared__ float T[47 * 33];
    const int tr0 = blockIdx.y * 32, tc0 = blockIdx.x * 32;
    const int zz = blockIdx.z;
    if (zz < 4) {
        daTileBody<8>(panf + (long)zz * HWSZ, da_pan8 + (long)zz * HWSZ,
                      tr0, tc0, RAW, T);
    } else {
        const int b = zz - 4;
        daTileBody<2>(labels + ((long)b * 9 + 8) * HWSZ,
                      db_pan2 + (long)b * HWSZ, tr0, tc0, RAW, T);
    }
}

// Grid-concat of k_sq<8> (da_pan8) and k_sq<2> (db_pan2). grid (16,16,8).
__global__ __launch_bounds__(256) void kSQduo(const float* __restrict__ da_pan8,
                                              const float* __restrict__ db_pan2,
                                              float* __restrict__ saa8,
                                              float* __restrict__ sbb2) {
    __shared__ float RAW[47 * 47];
    __shared__ float T[47 * 33];
    const int tr0 = blockIdx.y * 32, tc0 = blockIdx.x * 32;
    const int zz = blockIdx.z;
    if (zz < 4) {
        sqTileBody<8>(da_pan8 + (long)zz * HWSZ, saa8 + (long)zz * HWSZ,
                      tr0, tc0, RAW, T);
    } else {
        const int b = zz - 4;
        sqTileBody<2>(db_pan2 + (long)b * HWSZ, sbb2 + (long)b * HWSZ,
                      tr0, tc0, RAW, T);
    }
}

// ---------------------------------------------------------------------------
// Sliding-window helpers for the full-size (32-image) path.

template <int W> struct WinDims {
    static constexpr int A  = (W + 3) & ~3;
    static constexpr int NU = A + W + 8;              // elements actually used
    static constexpr int NF = (NU + 3) / 4;           // 4-elem chunks loaded
    static constexpr int NV = NF * 4;                 // padded array size
};

template <int W>
__device__ __forceinline__ void loadRowWin(const float* __restrict__ row, int c0,
                                           float* v) {
    constexpr int A = WinDims<W>::A;
    constexpr int NF = WinDims<W>::NF;
#pragma unroll
    for (int f = 0; f < NF; ++f) {
        const int cb = c0 - A + 4 * f;
        if (cb >= 0 && cb + 3 < IMG) {
            const float4 t = *(const float4*)(row + cb);
            v[4 * f + 0] = t.x; v[4 * f + 1] = t.y;
            v[4 * f + 2] = t.z; v[4 * f + 3] = t.w;
        } else {
#pragma unroll
            for (int u = 0; u < 4; ++u) {
                const int c = cb + u;
                v[4 * f + u] = (c >= 0 && c < IMG) ? row[c] : 0.f;
            }
        }
    }
}

template <int W>
__device__ __forceinline__ void loadRowWinH(const half_t* __restrict__ row, int c0,
                                            float* v) {
    constexpr int A = WinDims<W>::A;
    constexpr int NF = WinDims<W>::NF;
#pragma unroll
    for (int f = 0; f < NF; ++f) {
        const int cb = c0 - A + 4 * f;   // multiple of 4 -> 8B aligned
        if (cb >= 0 && cb + 3 < IMG) {
            const half4v t = *(const half4v*)(row + cb);
            v[4 * f + 0] = (float)t[0]; v[4 * f + 1] = (float)t[1];
            v[4 * f + 2] = (float)t[2]; v[4 * f + 3] = (float)t[3];
        } else {
#pragma unroll
            for (int u = 0; u < 4; ++u) {
                const int c = cb + u;
                v[4 * f + u] = (c >= 0 && c < IMG) ? (float)row[c] : 0.f;
            }
        }
    }
}

// ---------------------------------------------------------------------------
// XCD-aware decode for the full-size tile kernels (2048-block flat grids).
__device__ __forceinline__ void xcdDecode(int id, int& z, int& tr0, int& tc0) {
    const int xcd = id & 7, inner = id >> 3;
    z = (xcd << 2) | (inner >> 6);
    const int t = inner & 63;
    tr0 = (t >> 3) * 64;
    tc0 = (t & 7) * 64;
}

// ---------------------------------------------------------------------------
// kDApair: grid-concat of kDAtile<8>(inp ms) and kDAspec(outputs). Blocks
// 0..2047 run the w=8 da tile; 2048..4095 run the w=2 da tile + spec H-conv.
// grid 4096 x 256.
__global__ __launch_bounds__(256) void kDApair(const float* __restrict__ inp,
                                               const float* __restrict__ outputs,
                                               const float* __restrict__ mtf,
                                               half_t* __restrict__ hDA8,
                                               half_t* __restrict__ hDA2,
                                               float* __restrict__ tmpS) {
    constexpr int LP = 65;
    __shared__ float BUF[79 * LP];                // 20540 B, max of both halves
    const int half = blockIdx.x >> 11;
    int z, tr0, tc0;
    xcdDecode(blockIdx.x & 2047, z, tr0, tc0);
    const int c = threadIdx.x & 63, q = threadIdx.x >> 6;
    const int ro0 = q * 16;

    if (half == 0) {
        // ---------------- kDAtile<8> body (inp ms bands) -----------------
        constexpr int W = 8;
        constexpr int A = WinDims<W>::A;
        constexpr int NV = WinDims<W>::NV;
        constexpr int NRS = 63 + 2 * W;           // 79
        constexpr int NN = 4 * W * W;
        float* T = BUF;
        const float* img = inp + ((long)(z >> 3) * 9 + (z & 7)) * HWSZ;

        for (int e = threadIdx.x; e < NRS * 8; e += 256) {
            const int i = e >> 3, cg = e & 7;
            const int gr = tr0 - W + 1 + i;
            float* dst = &T[i * LP + cg * 8];
            if (gr < 0 || gr >= IMG) {
#pragma unroll
                for (int j = 0; j < 8; ++j) dst[j] = 0.f;
                continue;
            }
            float v[NV];
            loadRowWin<W>(img + (long)gr * IMG, tc0 + cg * 8, v);
            float s = 0.f;
#pragma unroll
            for (int k = A - W + 1; k <= A + W; ++k) s += v[k];
            dst[0] = s;
#pragma unroll
            for (int j = 1; j < 8; ++j) {
                s += v[A + W + j] - v[A - W + j];
                dst[j] = s;
            }
        }
        __syncthreads();

        float s = 0.f;
#pragma unroll
        for (int k = 0; k < 2 * W; ++k) s += T[(ro0 + k) * LP + c];
        const float* oz = img + tc0 + c;
        half_t* dz = hDA8 + (long)z * HWSZ + tc0 + c;
#pragma unroll
        for (int j = 0; j < 16; ++j) {
            const int r = tr0 + ro0 + j;
            const float o = oz[(long)r * IMG];
            dz[(long)r * IMG] = (half_t)(o - s * (1.0f / NN));
            if (j < 15) s += T[(ro0 + j + 2 * W) * LP + c] - T[(ro0 + j) * LP + c];
        }
    } else {
        // ---------------- kDAspec body (outputs) -------------------------
        constexpr int W = 2;
        constexpr int A = WinDims<W>::A;
        constexpr int NV = WinDims<W>::NV;
        constexpr int NRS = 63 + 2 * W;           // 67
        constexpr int NN = 4 * W * W;
        float* T = BUF;                           // 67*65 floats
        float* vrow = BUF + 67 * LP;              // 41 floats, past T
        const int band = z & 7;
        if (threadIdx.x < 41)
            vrow[threadIdx.x] = mtf[band * 1681 + 20 * 41 + threadIdx.x] /
                                sqrtf(mtf[band * 1681 + 20 * 41 + 20]);
        const float* img = outputs + (long)z * HWSZ;

        // phase 1: t = H-box(raw)
        for (int e = threadIdx.x; e < NRS * 8; e += 256) {
            const int i = e >> 3, cg = e & 7;
            const int gr = tr0 - W + 1 + i;
            float* dst = &T[i * LP + cg * 8];
            if (gr < 0 || gr >= IMG) {
#pragma unroll
                for (int j = 0; j < 8; ++j) dst[j] = 0.f;
                continue;
            }
            float v[NV];
            loadRowWin<W>(img + (long)gr * IMG, tc0 + cg * 8, v);
            float s = 0.f;
#pragma unroll
            for (int k = A - W + 1; k <= A + W; ++k) s += v[k];
            dst[0] = s;
#pragma unroll
            for (int j = 1; j < 8; ++j) {
                s += v[A + W + j] - v[A - W + j];
                dst[j] = s;
            }
        }
        __syncthreads();   // also publishes vrow

        // phase 2: V-slide + da epilogue
        float s = 0.f;
#pragma unroll
        for (int k = 0; k < 2 * W; ++k) s += T[(ro0 + k) * LP + c];
        const float* oz = img + tc0 + c;
        half_t* dz = hDA2 + (long)z * HWSZ + tc0 + c;
#pragma unroll
        for (int j = 0; j < 16; ++j) {
            const int r = tr0 + ro0 + j;
            const float o = oz[(long)r * IMG];
            dz[(long)r * IMG] = (half_t)(o - s * (1.0f / NN));
            if (j < 15) s += T[(ro0 + j + 2 * W) * LP + c] - T[(ro0 + j) * LP + c];
        }

        // phase 3: spec H-conv, k_spec_h register-window body on the tile.
        {
            const int r = threadIdx.x >> 2, u = threadIdx.x & 3;
            const float* row = img + (long)(tr0 + r) * IMG;
            float v[56];
#pragma unroll
            for (int f = 0; f < 14; ++f) {
                const int cb = tc0 + 16 * u - 20 + 4 * f;
                if (cb >= 0 && cb + 3 < IMG) {
                    const float4 t = *(const float4*)(row + cb);
                    v[4 * f + 0] = t.x; v[4 * f + 1] = t.y;
                    v[4 * f + 2] = t.z; v[4 * f + 3] = t.w;
                } else {
#pragma unroll
                    for (int uu = 0; uu < 4; ++uu) {
                        const int cc = cb + uu;
                        v[4 * f + uu] = (cc >= 0 && cc < IMG) ? row[cc] : 0.f;
                    }
                }
            }
            float o[4] = {0.f, 0.f, 0.f, 0.f};
#pragma unroll
            for (int j = 0; j < 41; ++j) {
                const float w = vrow[j];
#pragma unroll
                for (int uu = 0; uu < 4; ++uu) o[uu] += w * v[2 + 4 * uu + j];
            }
            float* ts = tmpS + ((long)z * IMG + tr0 + r) * 128 + (tc0 >> 2) + 4 * u;
            *(float4*)ts = make_float4(o[0], o[1], o[2], o[3]);
        }
    }
}

// ---------------------------------------------------------------------------
// Fused product + H-box staging: per 64x64 tile, H-box of (da*dshared, da*da)
// rows into LDS as packed half2(p1,p2).
template <int W>
__device__ __forceinline__ void stageProducts(const half_t* __restrict__ daz,
                                              const float* __restrict__ dsz,
                                              int tr0, int tc0,
                                              unsigned int* L) {
    constexpr int A = WinDims<W>::A;
    constexpr int NU = WinDims<W>::NU;
    constexpr int NV = WinDims<W>::NV;
    constexpr int NRS = 63 + 2 * W;               // staged product rows
    constexpr int LP = 65;                        // uint pitch (4B units)
    for (int e = threadIdx.x; e < NRS * 8; e += 256) {
        const int i = e >> 3, cg = e & 7;
        const int gr = tr0 - W + 1 + i;
        const int c0 = tc0 + cg * 8;
        unsigned int* dst = L + i * LP + cg * 8;
        if (gr < 0 || gr >= IMG) {
#pragma unroll
            for (int j = 0; j < 8; ++j) dst[j] = 0u;
            continue;
        }
        float va[NV], vs[NV];
        loadRowWinH<W>(daz + (long)gr * IMG, c0, va);
        loadRowWin<W>(dsz + (long)gr * IMG, c0, vs);
        float p1[NV], p2[NV];
#pragma unroll
        for (int k = 0; k < NU; ++k) { p1[k] = va[k] * vs[k]; p2[k] = va[k] * va[k]; }
        float s1 = 0.f, s2 = 0.f;
#pragma unroll
        for (int k = A - W + 1; k <= A + W; ++k) { s1 += p1[k]; s2 += p2[k]; }
#pragma unroll
        for (int j = 0; j < 8; ++j) {
            half2v h;
            h[0] = (half_t)s1; h[1] = (half_t)s2;
            dst[j] = __builtin_bit_cast(unsigned int, h);
            if (j < 7) {
                s1 += p1[A + W + 1 + j] - p1[A - W + 1 + j];
                s2 += p2[A + W + 1 + j] - p2[A - W + 1 + j];
            }
        }
    }
}

// ---------------------------------------------------------------------------
// kXYspec: grid-concat of kFusedXY (blocks 0..2047) and k_spec_v (blocks
// 2048..2559). Bodies byte-identical to the round-15 kernels; they write
// disjoint accumulators (acc[2] vs acc[0..1]) and are mutually independent.
// The 512 spec blocks fill the XY wave's ramp/tail on the single stream.
// LDS = XY buffers (38 KB) + spec ucol/red (~0.3 KB) -> still 4 blocks/CU.
// grid 2560 x 256.
__global__ __launch_bounds__(256, 4) void kXYspec(
    const half_t* __restrict__ daMS,
    const float* __restrict__ daPAN,
    const float* __restrict__ saa,
    const half_t* __restrict__ daOUT,
    const float* __restrict__ dbPAN,
    const float* __restrict__ sbb,
    const float* __restrict__ tmpS,
    const float* __restrict__ labels,
    const float* __restrict__ spec,
    const float* __restrict__ mtf,
    double* __restrict__ acc) {
    constexpr int LP = 65;
    constexpr int NRS8 = 63 + 16;                 // 79 (w=8)
    constexpr int NRS2 = 63 + 4;                  // 67 (w=2)
    __shared__ unsigned int L8[NRS8 * LP];
    __shared__ unsigned int L2b[NRS2 * LP];
    __shared__ double red[4];
    __shared__ double redM[4];
    __shared__ float ucol[41];

    if (blockIdx.x < 2048) {
        // ================= kFusedXY body =================
        int z, tr0, tc0;
        xcdDecode(blockIdx.x, z, tr0, tc0);
        const int b = z >> 3;
        const int c = threadIdx.x & 63, q = threadIdx.x >> 6;
        const int ro0 = q * 16;

        stageProducts<8>(daMS + (long)z * HWSZ, daPAN + (long)b * HWSZ,
                         tr0, tc0, L8);
        stageProducts<2>(daOUT + (long)z * HWSZ, dbPAN + (long)b * HWSZ,
                         tr0, tc0, L2b);
        __syncthreads();

        float thrv[16];
        {   // w = 8: thr
            constexpr int W = 8;
            float s1 = 0.f, s2 = 0.f;
#pragma unroll
            for (int k = 0; k < 2 * W; ++k) {
                const half2v h = __builtin_bit_cast(half2v, L8[(ro0 + k) * LP + c]);
                s1 += (float)h[0]; s2 += (float)h[1];
            }
            const float* sz = saa + (long)b * HWSZ + tc0 + c;
#pragma unroll
            for (int j = 0; j < 16; ++j) {
                const int r = tr0 + ro0 + j;
                const float sa = sz[(long)r * IMG];
                const float den = sqrtf(fmaxf(sa * s2, 0.f)) + 1e-20f;
                thrv[j] = 1.0f - s1 / den;
                if (j < 15) {
                    const half2v ha = __builtin_bit_cast(half2v, L8[(ro0 + j + 2 * W) * LP + c]);
                    const half2v hs = __builtin_bit_cast(half2v, L8[(ro0 + j) * LP + c]);
                    s1 += (float)ha[0] - (float)hs[0];
                    s2 += (float)ha[1] - (float)hs[1];
                }
            }
        }
        double ysum = 0.0;
        {   // w = 2: X vs thr, Y
            constexpr int W = 2;
            float s1 = 0.f, s2 = 0.f;
#pragma unroll
            for (int k = 0; k < 2 * W; ++k) {
                const half2v h = __builtin_bit_cast(half2v, L2b[(ro0 + k) * LP + c]);
                s1 += (float)h[0]; s2 += (float)h[1];
            }
            const float* sz = sbb + (long)b * HWSZ + tc0 + c;
#pragma unroll
            for (int j = 0; j < 16; ++j) {
                const float sb = sz[(long)(tr0 + ro0 + j) * IMG];
                const float den = sqrtf(fmaxf(s2 * sb, 0.f)) + 1e-20f;
                const float Xc = s1 / den;
                const float X = 1.0f - fmaxf(Xc, -1.0f);
                if (X > thrv[j]) ysum += (double)X;
                if (j < 15) {
                    const half2v ha = __builtin_bit_cast(half2v, L2b[(ro0 + j + 2 * W) * LP + c]);
                    const half2v hs = __builtin_bit_cast(half2v, L2b[(ro0 + j) * LP + c]);
                    s1 += (float)ha[0] - (float)hs[0];
                    s2 += (float)ha[1] - (float)hs[1];
                }
            }
        }
        blockReduceAtomicAdd(ysum, acc + 2, red);
    } else {
        // ================= k_spec_v body =================
        const int g = (blockIdx.x - 2048) * 256 + threadIdx.x;
        const int q = g & 31, rs = (g >> 5) & 127, z = g >> 12;   // z uniform/block
        const int b = z >> 3, band = z & 7;
        if (threadIdx.x < 41)
            ucol[threadIdx.x] = mtf[band * 1681 + threadIdx.x * 41 + 20] /
                                sqrtf(mtf[band * 1681 + 20 * 41 + 20]);
        __syncthreads();
        const float* base = tmpS + (long)z * IMG * 128 + 4 * q;
        const int rbase = 4 * rs - 18;
        float o[4] = {0.f, 0.f, 0.f, 0.f};
        if (rbase >= 0 && rbase + 40 < IMG) {
#pragma unroll
            for (int i = 0; i < 41; ++i) {
                const float4 v = *(const float4*)(base + (long)(rbase + i) * 128);
                const float w = ucol[i];
                o[0] += w * v.x; o[1] += w * v.y; o[2] += w * v.z; o[3] += w * v.w;
            }
        } else {
            for (int i = 0; i < 41; ++i) {
                const int r = rbase + i;
                if (r >= 0 && r < IMG) {
                    const float4 v = *(const float4*)(base + (long)r * 128);
                    const float w = ucol[i];
                    o[0] += w * v.x; o[1] += w * v.y; o[2] += w * v.z; o[3] += w * v.w;
                }
            }
        }
        const int gr = 2 + 4 * rs;
        float tsum = 0.f, msum = 0.f;
#pragma unroll
        for (int u = 0; u < 4; ++u) {
            const int gc = 2 + 4 * (4 * q + u);
            const float m = spec[(long)band * HWSZ + (long)gr * IMG + gc];
            const float y = labels[((long)b * 9 + band) * HWSZ + (long)gr * IMG + gc];
            tsum += fabsf(o[u] * m - y * m);
            msum += m;
        }
        blockReduceAtomicAdd((double)tsum, acc + 0, red);
        blockReduceAtomicAdd((double)msum, acc + 1, redM);
    }
}

__global__ void k_final(const double* __restrict__ acc, float* __restrict__ out) {
    double lspec = acc[0] / acc[1];
    double lstruct = acc[2] / (double)(NBATCH * NBANDS * HWSZ);
    out[0] = (float)(lspec + 0.25 * lstruct);
}

// ---------------------------------------------------------------------------
extern "C" void kernel_launch(void* const* d_in, const int* in_sizes, int n_in,
                              void* d_out, int out_size, void* d_ws, size_t ws_size,
                              hipStream_t stream) {
    const float* outputs = (const float*)d_in[0];   // (4,8,512,512)
    const float* labels  = (const float*)d_in[1];   // (4,9,512,512)
    const float* inp     = (const float*)d_in[2];   // (4,9,512,512)
    const float* mtf     = (const float*)d_in[3];   // (8,1,41,41)
    const float* spec    = (const float*)d_in[4];   // (1,8,512,512)
    float* out = (float*)d_out;

    const long IMGB = (long)HWSZ;     // one image in elements
    char* ws = (char*)d_ws;
    double* acc    = (double*)ws;                    // 4 doubles
    float* panf    = (float*)(ws + 1024);            // 4 imgs fp32
    float* tmpH    = panf   + NBATCH * IMGB;         // 4 imgs
    float* da_pan8 = tmpH   + NBATCH * IMGB;         // 4 imgs
    float* saa8    = da_pan8 + NBATCH * IMGB;        // 4 imgs
    float* db_pan2 = saa8   + NBATCH * IMGB;         // 4 imgs
    float* sbb2    = db_pan2 + NBATCH * IMGB;        // 4 imgs
    float* tmpS    = sbb2   + NBATCH * IMGB;         // 8 imgs fp32
    half_t* hDA8   = (half_t*)(tmpS + 8 * IMGB);     // 32 imgs half: da_ms  (w=8)
    half_t* hDA2   = hDA8 + 32 * IMGB;               // 32 imgs half: da_out (w=2)

    hipMemsetAsync(acc, 0, 4 * sizeof(double), stream);

    // --- per-batch shared fields (fp32) ----------------------------------
    k_pan_h<<<dim3(2, 512, NBATCH), 256, 0, stream>>>(inp, mtf, tmpH);
    k_pan_v<<<dim3(2, 512, NBATCH), 256, 0, stream>>>(tmpH, mtf, panf);
    kDAduo<<<dim3(16, 16, 8), 256, 0, stream>>>(panf, labels, da_pan8, db_pan2);
    kSQduo<<<dim3(16, 16, 8), 256, 0, stream>>>(da_pan8, db_pan2, saa8, sbb2);

    // --- da fields (w=8) + fused da/spec-H (w=2), one dispatch -----------
    kDApair<<<4096, 256, 0, stream>>>(inp, outputs, mtf, hDA8, hDA2, tmpS);

    // --- structural XY + spec V pass, one dispatch ------------------------
    kXYspec<<<2560, 256, 0, stream>>>(hDA8, da_pan8, saa8,
                                      hDA2, db_pan2, sbb2,
                                      tmpS, labels, spec, mtf, acc);

    k_final<<<1, 1, 0, stream>>>(acc, out);
}

// Round 17
// 267.584 us; speedup vs baseline: 1.1619x; 1.0018x over previous
//
#include <hip/hip_runtime.h>
#include <hip/hip_bf16.h>

// Problem constants
#define HWSZ   262144   // 512*512
#define IMG    512
#define NBATCH 4
#define NBANDS 8

typedef _Float16 half_t;
typedef _Float16 half2v __attribute__((ext_vector_type(2)));
typedef _Float16 half4v __attribute__((ext_vector_type(4)));
typedef _Float16 half8v __attribute__((ext_vector_type(8)));

// ---------------------------------------------------------------------------
// Block-level reduction: wave shuffle + LDS + one double atomic per block.
__device__ __forceinline__ void blockReduceAtomicAdd(double v, double* target,
                                                     double* red) {
    for (int off = 32; off > 0; off >>= 1) v += __shfl_down(v, off, 64);
    const int wave = threadIdx.x >> 6, lane = threadIdx.x & 63;
    if (lane == 0) red[wave] = v;
    __syncthreads();
    if (threadIdx.x == 0) atomicAdd(target, red[0] + red[1] + red[2] + red[3]);
}

// ---------------------------------------------------------------------------
// Small-field (4-image) tile bodies (verbatim k_da / k_sq math).
template <int W>
__device__ __forceinline__ void daTileBody(const float* __restrict__ src,
                                           float* __restrict__ dst,
                                           int tr0, int tc0,
                                           float* RAW, float* T) {
    constexpr int TS = 32, WIN = 2 * W, NN = 4 * W * W, RE = TS + WIN - 1;
    constexpr int SR = RE, ST = 33;
    const int tid = threadIdx.x;
    for (int e = tid; e < RE * RE; e += 256) {
        int r = e / RE, c = e % RE;
        int gr = tr0 - (W - 1) + r, gc = tc0 - (W - 1) + c;
        float v = 0.f;
        if (gr >= 0 && gr < IMG && gc >= 0 && gc < IMG) v = src[(long)gr * IMG + gc];
        RAW[r * SR + c] = v;
    }
    __syncthreads();
    for (int e = tid; e < RE * TS; e += 256) {
        int r = e >> 5, j = e & 31;
        float s = 0.f;
#pragma unroll
        for (int k = 0; k < WIN; ++k) s += RAW[r * SR + j + k];
        T[r * ST + j] = s;
    }
    __syncthreads();
    for (int e = tid; e < TS * TS; e += 256) {
        int pr = e >> 5, pc = e & 31;
        float s = 0.f;
#pragma unroll
        for (int k = 0; k < WIN; ++k) s += T[(pr + k) * ST + pc];
        float da = RAW[(pr + W - 1) * SR + (pc + W - 1)] - s * (1.0f / NN);
        dst[(long)(tr0 + pr) * IMG + tc0 + pc] = da;
    }
}

template <int W>
__device__ __forceinline__ void sqTileBody(const float* __restrict__ src,
                                           float* __restrict__ dst,
                                           int tr0, int tc0,
                                           float* RAW, float* T) {
    constexpr int TS = 32, WIN = 2 * W, RE = TS + WIN - 1;
    constexpr int SR = RE, ST = 33;
    const int tid = threadIdx.x;
    for (int e = tid; e < RE * RE; e += 256) {
        int r = e / RE, c = e % RE;
        int gr = tr0 - (W - 1) + r, gc = tc0 - (W - 1) + c;
        float v = 0.f;
        if (gr >= 0 && gr < IMG && gc >= 0 && gc < IMG) v = src[(long)gr * IMG + gc];
        RAW[r * SR + c] = v;
    }
    __syncthreads();
    for (int e = tid; e < RE * TS; e += 256) {
        int r = e >> 5, j = e & 31;
        float s = 0.f;
#pragma unroll
        for (int k = 0; k < WIN; ++k) {
            float v = RAW[r * SR + j + k];
            s += v * v;
        }
        T[r * ST + j] = s;
    }
    __syncthreads();
    for (int e = tid; e < TS * TS; e += 256) {
        int pr = e >> 5, pc = e & 31;
        float s = 0.f;
#pragma unroll
        for (int k = 0; k < WIN; ++k) s += T[(pr + k) * ST + pc];
        dst[(long)(tr0 + pr) * IMG + tc0 + pc] = s;
    }
}

// Grid-concat of k_da<8> (panf) and k_da<2> (label pan). grid (16,16,8).
__global__ __launch_bounds__(256) void kDAduo(const float* __restrict__ panf,
                                              const float* __restrict__ labels,
                                              float* __restrict__ da_pan8,
                                              float* __restrict__ db_pan2) {
    __shared__ float RAW[47 * 47];
    __shared__ float T[47 * 33];
    const int tr0 = blockIdx.y * 32, tc0 = blockIdx.x * 32;
    const int zz = blockIdx.z;
    if (zz < 4) {
        daTileBody<8>(panf + (long)zz * HWSZ, da_pan8 + (long)zz * HWSZ,
                      tr0, tc0, RAW, T);
    } else {
        const int b = zz - 4;
        daTileBody<2>(labels + ((long)b * 9 + 8) * HWSZ,
                      db_pan2 + (long)b * HWSZ, tr0, tc0, RAW, T);
    }
}

// Grid-concat of k_sq<8> (da_pan8) and k_sq<2> (db_pan2). grid (16,16,8).
__global__ __launch_bounds__(256) void kSQduo(const float* __restrict__ da_pan8,
                                              const float* __restrict__ db_pan2,
                                              float* __restrict__ saa8,
                                              float* __restrict__ sbb2) {
    __shared__ float RAW[47 * 47];
    __shared__ float T[47 * 33];
    const int tr0 = blockIdx.y * 32, tc0 = blockIdx.x * 32;
    const int zz = blockIdx.z;
    if (zz < 4) {
        sqTileBody<8>(da_pan8 + (long)zz * HWSZ, saa8 + (long)zz * HWSZ,
                      tr0, tc0, RAW, T);
    } else {
        const int b = zz - 4;
        sqTileBody<2>(db_pan2 + (long)b * HWSZ, sbb2 + (long)b * HWSZ,
                      tr0, tc0, RAW, T);
    }
}

// ---------------------------------------------------------------------------
// Sliding-window helpers for the full-size (32-image) path.

template <int W> struct WinDims {
    static constexpr int A  = (W + 3) & ~3;
    static constexpr int NU = A + W + 8;              // elements actually used
    static constexpr int NF = (NU + 3) / 4;           // 4-elem chunks loaded
    static constexpr int NV = NF * 4;                 // padded array size
};

template <int W>
__device__ __forceinline__ void loadRowWin(const float* __restrict__ row, int c0,
                                           float* v) {
    constexpr int A = WinDims<W>::A;
    constexpr int NF = WinDims<W>::NF;
#pragma unroll
    for (int f = 0; f < NF; ++f) {
        const int cb = c0 - A + 4 * f;
        if (cb >= 0 && cb + 3 < IMG) {
            const float4 t = *(const float4*)(row + cb);
            v[4 * f + 0] = t.x; v[4 * f + 1] = t.y;
            v[4 * f + 2] = t.z; v[4 * f + 3] = t.w;
        } else {
#pragma unroll
            for (int u = 0; u < 4; ++u) {
                const int c = cb + u;
                v[4 * f + u] = (c >= 0 && c < IMG) ? row[c] : 0.f;
            }
        }
    }
}

template <int W>
__device__ __forceinline__ void loadRowWinH(const half_t* __restrict__ row, int c0,
                                            float* v) {
    constexpr int A = WinDims<W>::A;
    constexpr int NF = WinDims<W>::NF;
#pragma unroll
    for (int f = 0; f < NF; ++f) {
        const int cb = c0 - A + 4 * f;   // multiple of 4 -> 8B aligned
        if (cb >= 0 && cb + 3 < IMG) {
            const half4v t = *(const half4v*)(row + cb);
            v[4 * f + 0] = (float)t[0]; v[4 * f + 1] = (float)t[1];
            v[4 * f + 2] = (float)t[2]; v[4 * f + 3] = (float)t[3];
        } else {
#pragma unroll
            for (int u = 0; u < 4; ++u) {
                const int c = cb + u;
                v[4 * f + u] = (c >= 0 && c < IMG) ? (float)row[c] : 0.f;
            }
        }
    }
}

// ---------------------------------------------------------------------------
// XCD-aware decode for the full-size tile kernels (2048-block flat grids).
__device__ __forceinline__ void xcdDecode(int id, int& z, int& tr0, int& tc0) {
    const int xcd = id & 7, inner = id >> 3;
    z = (xcd << 2) | (inner >> 6);
    const int t = inner & 63;
    tr0 = (t >> 3) * 64;
    tc0 = (t & 7) * 64;
}

// ---------------------------------------------------------------------------
// kDAtile<8> body (verbatim round-16): H-box + V-box + da epilogue, 64x64
// tile, one barrier. T = 79*65 floats in the caller's shared buffer.
__device__ __forceinline__ void da8Body(const float* __restrict__ inp, int id,
                                        half_t* __restrict__ hDA8, float* T) {
    constexpr int W = 8;
    constexpr int A = WinDims<W>::A;
    constexpr int NV = WinDims<W>::NV;
    constexpr int NRS = 63 + 2 * W;               // 79
    constexpr int LP = 65;
    constexpr int NN = 4 * W * W;
    int z, tr0, tc0;
    xcdDecode(id, z, tr0, tc0);
    const int c = threadIdx.x & 63, q = threadIdx.x >> 6;
    const int ro0 = q * 16;
    const float* img = inp + ((long)(z >> 3) * 9 + (z & 7)) * HWSZ;

    for (int e = threadIdx.x; e < NRS * 8; e += 256) {
        const int i = e >> 3, cg = e & 7;
        const int gr = tr0 - W + 1 + i;
        float* dst = &T[i * LP + cg * 8];
        if (gr < 0 || gr >= IMG) {
#pragma unroll
            for (int j = 0; j < 8; ++j) dst[j] = 0.f;
            continue;
        }
        float v[NV];
        loadRowWin<W>(img + (long)gr * IMG, tc0 + cg * 8, v);
        float s = 0.f;
#pragma unroll
        for (int k = A - W + 1; k <= A + W; ++k) s += v[k];
        dst[0] = s;
#pragma unroll
        for (int j = 1; j < 8; ++j) {
            s += v[A + W + j] - v[A - W + j];
            dst[j] = s;
        }
    }
    __syncthreads();

    float s = 0.f;
#pragma unroll
    for (int k = 0; k < 2 * W; ++k) s += T[(ro0 + k) * LP + c];
    const float* oz = img + tc0 + c;
    half_t* dz = hDA8 + (long)z * HWSZ + tc0 + c;
#pragma unroll
    for (int j = 0; j < 16; ++j) {
        const int r = tr0 + ro0 + j;
        const float o = oz[(long)r * IMG];
        dz[(long)r * IMG] = (half_t)(o - s * (1.0f / NN));
        if (j < 15) s += T[(ro0 + j + 2 * W) * LP + c] - T[(ro0 + j) * LP + c];
    }
}

// kDAspec body (verbatim round-16): w=2 da tile + spec H-conv.
// BUF = 79*65 floats (T uses 67*65; vrow aliased past it).
__device__ __forceinline__ void daSpecBody(const float* __restrict__ outputs,
                                           const float* __restrict__ mtf, int id,
                                           half_t* __restrict__ hDA2,
                                           float* __restrict__ tmpS, float* BUF) {
    constexpr int W = 2;
    constexpr int A = WinDims<W>::A;
    constexpr int NV = WinDims<W>::NV;
    constexpr int NRS = 63 + 2 * W;               // 67
    constexpr int LP = 65;
    constexpr int NN = 4 * W * W;
    float* T = BUF;
    float* vrow = BUF + 67 * LP;
    int z, tr0, tc0;
    xcdDecode(id, z, tr0, tc0);
    const int c = threadIdx.x & 63, q = threadIdx.x >> 6;
    const int ro0 = q * 16;
    const int band = z & 7;
    if (threadIdx.x < 41)
        vrow[threadIdx.x] = mtf[band * 1681 + 20 * 41 + threadIdx.x] /
                            sqrtf(mtf[band * 1681 + 20 * 41 + 20]);
    const float* img = outputs + (long)z * HWSZ;

    // phase 1: t = H-box(raw)
    for (int e = threadIdx.x; e < NRS * 8; e += 256) {
        const int i = e >> 3, cg = e & 7;
        const int gr = tr0 - W + 1 + i;
        float* dst = &T[i * LP + cg * 8];
        if (gr < 0 || gr >= IMG) {
#pragma unroll
            for (int j = 0; j < 8; ++j) dst[j] = 0.f;
            continue;
        }
        float v[NV];
        loadRowWin<W>(img + (long)gr * IMG, tc0 + cg * 8, v);
        float s = 0.f;
#pragma unroll
        for (int k = A - W + 1; k <= A + W; ++k) s += v[k];
        dst[0] = s;
#pragma unroll
        for (int j = 1; j < 8; ++j) {
            s += v[A + W + j] - v[A - W + j];
            dst[j] = s;
        }
    }
    __syncthreads();   // also publishes vrow

    // phase 2: V-slide + da epilogue
    float s = 0.f;
#pragma unroll
    for (int k = 0; k < 2 * W; ++k) s += T[(ro0 + k) * LP + c];
    const float* oz = img + tc0 + c;
    half_t* dz = hDA2 + (long)z * HWSZ + tc0 + c;
#pragma unroll
    for (int j = 0; j < 16; ++j) {
        const int r = tr0 + ro0 + j;
        const float o = oz[(long)r * IMG];
        dz[(long)r * IMG] = (half_t)(o - s * (1.0f / NN));
        if (j < 15) s += T[(ro0 + j + 2 * W) * LP + c] - T[(ro0 + j) * LP + c];
    }

    // phase 3: spec H-conv, k_spec_h register-window body on the tile.
    {
        const int r = threadIdx.x >> 2, u = threadIdx.x & 3;
        const float* row = img + (long)(tr0 + r) * IMG;
        float v[56];
#pragma unroll
        for (int f = 0; f < 14; ++f) {
            const int cb = tc0 + 16 * u - 20 + 4 * f;
            if (cb >= 0 && cb + 3 < IMG) {
                const float4 t = *(const float4*)(row + cb);
                v[4 * f + 0] = t.x; v[4 * f + 1] = t.y;
                v[4 * f + 2] = t.z; v[4 * f + 3] = t.w;
            } else {
#pragma unroll
                for (int uu = 0; uu < 4; ++uu) {
                    const int cc = cb + uu;
                    v[4 * f + uu] = (cc >= 0 && cc < IMG) ? row[cc] : 0.f;
                }
            }
        }
        float o[4] = {0.f, 0.f, 0.f, 0.f};
#pragma unroll
        for (int j = 0; j < 41; ++j) {
            const float w = vrow[j];
#pragma unroll
            for (int uu = 0; uu < 4; ++uu) o[uu] += w * v[2 + 4 * uu + j];
        }
        float* ts = tmpS + ((long)z * IMG + tr0 + r) * 128 + (tc0 >> 2) + 4 * u;
        *(float4*)ts = make_float4(o[0], o[1], o[2], o[3]);
    }
}

// ---------------------------------------------------------------------------
// kPanDA1: grid-concat of k_pan_h (blocks 0..4095, flat-decoded bijection of
// the old (2,512,4) grid) and the kDAtile<8> half (blocks 4096..6143).
// Independent: pan_h writes tmpH, da8 writes hDA8. grid 6144 x 256.
__global__ __launch_bounds__(256) void kPanDA1(const float* __restrict__ inp,
                                               const float* __restrict__ mtf,
                                               float* __restrict__ tmpH,
                                               half_t* __restrict__ hDA8) {
    __shared__ float BUF[79 * 65];
    if (blockIdx.x < 4096) {
        // ---------------- k_pan_h body (verbatim, flat decode) -----------
        float* seg = BUF;            // 296 floats
        float* vrow = BUF + 296;     // 41 floats
        const int tid = threadIdx.x;
        const int e = blockIdx.x;
        const int c0 = (e & 1) * 256, r = (e >> 1) & 511, b = e >> 10;
        if (tid < 41) vrow[tid] = mtf[20 * 41 + tid] / sqrtf(mtf[20 * 41 + 20]);
        const float* pan = inp + ((long)b * 9 + 8) * HWSZ + (long)r * IMG;
        for (int k = tid; k < 296; k += 256) {
            int c = c0 - 20 + k;
            c = min(max(c, 0), IMG - 1);
            seg[k] = pan[c];
        }
        __syncthreads();
        float s = 0.f;
#pragma unroll
        for (int j = 0; j < 41; ++j) s += vrow[j] * seg[tid + j];
        tmpH[(long)b * HWSZ + (long)r * IMG + c0 + tid] = s;
    } else {
        da8Body(inp, blockIdx.x - 4096, hDA8, BUF);
    }
}

// kPanDA2: grid-concat of k_pan_v (blocks 0..4095) and the kDAspec half
// (blocks 4096..6143). pan_v reads tmpH (ready), writes panf; daspec writes
// hDA2/tmpS. grid 6144 x 256.
__global__ __launch_bounds__(256) void kPanDA2(const float* __restrict__ tmpH,
                                               const float* __restrict__ outputs,
                                               const float* __restrict__ mtf,
                                               float* __restrict__ panf,
                                               half_t* __restrict__ hDA2,
                                               float* __restrict__ tmpS) {
    __shared__ float BUF[79 * 65];
    if (blockIdx.x < 4096) {
        // ---------------- k_pan_v body (verbatim, flat decode) -----------
        float* ucol = BUF;           // 41 floats
        const int tid = threadIdx.x;
        const int e = blockIdx.x;
        const int c = (e & 1) * 256 + tid, r = (e >> 1) & 511, b = e >> 10;
        if (tid < 41) ucol[tid] = mtf[tid * 41 + 20] / sqrtf(mtf[20 * 41 + 20]);
        __syncthreads();
        const float* base = tmpH + (long)b * HWSZ;
        float s = 0.f;
#pragma unroll
        for (int i = 0; i < 41; ++i) {
            int rr = min(max(r - 20 + i, 0), IMG - 1);
            s += ucol[i] * base[(long)rr * IMG + c];
        }
        panf[(long)b * HWSZ + (long)r * IMG + c] = s;
    } else {
        daSpecBody(outputs, mtf, blockIdx.x - 4096, hDA2, tmpS, BUF);
    }
}

// ---------------------------------------------------------------------------
// Fused product + H-box staging: per 64x64 tile, H-box of (da*dshared, da*da)
// rows into LDS as packed half2(p1,p2).
template <int W>
__device__ __forceinline__ void stageProducts(const half_t* __restrict__ daz,
                                              const float* __restrict__ dsz,
                                              int tr0, int tc0,
                                              unsigned int* L) {
    constexpr int A = WinDims<W>::A;
    constexpr int NU = WinDims<W>::NU;
    constexpr int NV = WinDims<W>::NV;
    constexpr int NRS = 63 + 2 * W;               // staged product rows
    constexpr int LP = 65;                        // uint pitch (4B units)
    for (int e = threadIdx.x; e < NRS * 8; e += 256) {
        const int i = e >> 3, cg = e & 7;
        const int gr = tr0 - W + 1 + i;
        const int c0 = tc0 + cg * 8;
        unsigned int* dst = L + i * LP + cg * 8;
        if (gr < 0 || gr >= IMG) {
#pragma unroll
            for (int j = 0; j < 8; ++j) dst[j] = 0u;
            continue;
        }
        float va[NV], vs[NV];
        loadRowWinH<W>(daz + (long)gr * IMG, c0, va);
        loadRowWin<W>(dsz + (long)gr * IMG, c0, vs);
        float p1[NV], p2[NV];
#pragma unroll
        for (int k = 0; k < NU; ++k) { p1[k] = va[k] * vs[k]; p2[k] = va[k] * va[k]; }
        float s1 = 0.f, s2 = 0.f;
#pragma unroll
        for (int k = A - W + 1; k <= A + W; ++k) { s1 += p1[k]; s2 += p2[k]; }
#pragma unroll
        for (int j = 0; j < 8; ++j) {
            half2v h;
            h[0] = (half_t)s1; h[1] = (half_t)s2;
            dst[j] = __builtin_bit_cast(unsigned int, h);
            if (j < 7) {
                s1 += p1[A + W + 1 + j] - p1[A - W + 1 + j];
                s2 += p2[A + W + 1 + j] - p2[A - W + 1 + j];
            }
        }
    }
}

// ---------------------------------------------------------------------------
// kXYspec: grid-concat of kFusedXY (blocks 0..2047) and k_spec_v (blocks
// 2048..2559). grid 2560 x 256 (round-16 verified).
__global__ __launch_bounds__(256, 4) void kXYspec(
    const half_t* __restrict__ daMS,
    const float* __restrict__ daPAN,
    const float* __restrict__ saa,
    const half_t* __restrict__ daOUT,
    const float* __restrict__ dbPAN,
    const float* __restrict__ sbb,
    const float* __restrict__ tmpS,
    const float* __restrict__ labels,
    const float* __restrict__ spec,
    const float* __restrict__ mtf,
    double* __restrict__ acc) {
    constexpr int LP = 65;
    constexpr int NRS8 = 63 + 16;                 // 79 (w=8)
    constexpr int NRS2 = 63 + 4;                  // 67 (w=2)
    __shared__ unsigned int L8[NRS8 * LP];
    __shared__ unsigned int L2b[NRS2 * LP];
    __shared__ double red[4];
    __shared__ double redM[4];
    __shared__ float ucol[41];

    if (blockIdx.x < 2048) {
        // ================= kFusedXY body =================
        int z, tr0, tc0;
        xcdDecode(blockIdx.x, z, tr0, tc0);
        const int b = z >> 3;
        const int c = threadIdx.x & 63, q = threadIdx.x >> 6;
        const int ro0 = q * 16;

        stageProducts<8>(daMS + (long)z * HWSZ, daPAN + (long)b * HWSZ,
                         tr0, tc0, L8);
        stageProducts<2>(daOUT + (long)z * HWSZ, dbPAN + (long)b * HWSZ,
                         tr0, tc0, L2b);
        __syncthreads();

        float thrv[16];
        {   // w = 8: thr
            constexpr int W = 8;
            float s1 = 0.f, s2 = 0.f;
#pragma unroll
            for (int k = 0; k < 2 * W; ++k) {
                const half2v h = __builtin_bit_cast(half2v, L8[(ro0 + k) * LP + c]);
                s1 += (float)h[0]; s2 += (float)h[1];
            }
            const float* sz = saa + (long)b * HWSZ + tc0 + c;
#pragma unroll
            for (int j = 0; j < 16; ++j) {
                const int r = tr0 + ro0 + j;
                const float sa = sz[(long)r * IMG];
                const float den = sqrtf(fmaxf(sa * s2, 0.f)) + 1e-20f;
                thrv[j] = 1.0f - s1 / den;
                if (j < 15) {
                    const half2v ha = __builtin_bit_cast(half2v, L8[(ro0 + j + 2 * W) * LP + c]);
                    const half2v hs = __builtin_bit_cast(half2v, L8[(ro0 + j) * LP + c]);
                    s1 += (float)ha[0] - (float)hs[0];
                    s2 += (float)ha[1] - (float)hs[1];
                }
            }
        }
        double ysum = 0.0;
        {   // w = 2: X vs thr, Y
            constexpr int W = 2;
            float s1 = 0.f, s2 = 0.f;
#pragma unroll
            for (int k = 0; k < 2 * W; ++k) {
                const half2v h = __builtin_bit_cast(half2v, L2b[(ro0 + k) * LP + c]);
                s1 += (float)h[0]; s2 += (float)h[1];
            }
            const float* sz = sbb + (long)b * HWSZ + tc0 + c;
#pragma unroll
            for (int j = 0; j < 16; ++j) {
                const float sb = sz[(long)(tr0 + ro0 + j) * IMG];
                const float den = sqrtf(fmaxf(s2 * sb, 0.f)) + 1e-20f;
                const float Xc = s1 / den;
                const float X = 1.0f - fmaxf(Xc, -1.0f);
                if (X > thrv[j]) ysum += (double)X;
                if (j < 15) {
                    const half2v ha = __builtin_bit_cast(half2v, L2b[(ro0 + j + 2 * W) * LP + c]);
                    const half2v hs = __builtin_bit_cast(half2v, L2b[(ro0 + j) * LP + c]);
                    s1 += (float)ha[0] - (float)hs[0];
                    s2 += (float)ha[1] - (float)hs[1];
                }
            }
        }
        blockReduceAtomicAdd(ysum, acc + 2, red);
    } else {
        // ================= k_spec_v body =================
        const int g = (blockIdx.x - 2048) * 256 + threadIdx.x;
        const int q = g & 31, rs = (g >> 5) & 127, z = g >> 12;   // z uniform/block
        const int b = z >> 3, band = z & 7;
        if (threadIdx.x < 41)
            ucol[threadIdx.x] = mtf[band * 1681 + threadIdx.x * 41 + 20] /
                                sqrtf(mtf[band * 1681 + 20 * 41 + 20]);
        __syncthreads();
        const float* base = tmpS + (long)z * IMG * 128 + 4 * q;
        const int rbase = 4 * rs - 18;
        float o[4] = {0.f, 0.f, 0.f, 0.f};
        if (rbase >= 0 && rbase + 40 < IMG) {
#pragma unroll
            for (int i = 0; i < 41; ++i) {
                const float4 v = *(const float4*)(base + (long)(rbase + i) * 128);
                const float w = ucol[i];
                o[0] += w * v.x; o[1] += w * v.y; o[2] += w * v.z; o[3] += w * v.w;
            }
        } else {
            for (int i = 0; i < 41; ++i) {
                const int r = rbase + i;
                if (r >= 0 && r < IMG) {
                    const float4 v = *(const float4*)(base + (long)r * 128);
                    const float w = ucol[i];
                    o[0] += w * v.x; o[1] += w * v.y; o[2] += w * v.z; o[3] += w * v.w;
                }
            }
        }
        const int gr = 2 + 4 * rs;
        float tsum = 0.f, msum = 0.f;
#pragma unroll
        for (int u = 0; u < 4; ++u) {
            const int gc = 2 + 4 * (4 * q + u);
            const float m = spec[(long)band * HWSZ + (long)gr * IMG + gc];
            const float y = labels[((long)b * 9 + band) * HWSZ + (long)gr * IMG + gc];
            tsum += fabsf(o[u] * m - y * m);
            msum += m;
        }
        blockReduceAtomicAdd((double)tsum, acc + 0, red);
        blockReduceAtomicAdd((double)msum, acc + 1, redM);
    }
}

__global__ void k_final(const double* __restrict__ acc, float* __restrict__ out) {
    double lspec = acc[0] / acc[1];
    double lstruct = acc[2] / (double)(NBATCH * NBANDS * HWSZ);
    out[0] = (float)(lspec + 0.25 * lstruct);
}

// ---------------------------------------------------------------------------
extern "C" void kernel_launch(void* const* d_in, const int* in_sizes, int n_in,
                              void* d_out, int out_size, void* d_ws, size_t ws_size,
                              hipStream_t stream) {
    const float* outputs = (const float*)d_in[0];   // (4,8,512,512)
    const float* labels  = (const float*)d_in[1];   // (4,9,512,512)
    const float* inp     = (const float*)d_in[2];   // (4,9,512,512)
    const float* mtf     = (const float*)d_in[3];   // (8,1,41,41)
    const float* spec    = (const float*)d_in[4];   // (1,8,512,512)
    float* out = (float*)d_out;

    const long IMGB = (long)HWSZ;     // one image in elements
    char* ws = (char*)d_ws;
    double* acc    = (double*)ws;                    // 4 doubles
    float* panf    = (float*)(ws + 1024);            // 4 imgs fp32
    float* tmpH    = panf   + NBATCH * IMGB;         // 4 imgs
    float* da_pan8 = tmpH   + NBATCH * IMGB;         // 4 imgs
    float* saa8    = da_pan8 + NBATCH * IMGB;        // 4 imgs
    float* db_pan2 = saa8   + NBATCH * IMGB;         // 4 imgs
    float* sbb2    = db_pan2 + NBATCH * IMGB;        // 4 imgs
    float* tmpS    = sbb2   + NBATCH * IMGB;         // 8 imgs fp32
    half_t* hDA8   = (half_t*)(tmpS + 8 * IMGB);     // 32 imgs half: da_ms  (w=8)
    half_t* hDA2   = hDA8 + 32 * IMGB;               // 32 imgs half: da_out (w=2)

    hipMemsetAsync(acc, 0, 4 * sizeof(double), stream);

    // --- pan H-pass || w=8 da tiles (independent halves) -------------------
    kPanDA1<<<6144, 256, 0, stream>>>(inp, mtf, tmpH, hDA8);
    // --- pan V-pass || w=2 da tiles + spec H-conv (independent halves) -----
    kPanDA2<<<6144, 256, 0, stream>>>(tmpH, outputs, mtf, panf, hDA2, tmpS);

    // --- per-batch shared fields ------------------------------------------
    kDAduo<<<dim3(16, 16, 8), 256, 0, stream>>>(panf, labels, da_pan8, db_pan2);
    kSQduo<<<dim3(16, 16, 8), 256, 0, stream>>>(da_pan8, db_pan2, saa8, sbb2);

    // --- structural XY + spec V pass, one dispatch ------------------------
    kXYspec<<<2560, 256, 0, stream>>>(hDA8, da_pan8, saa8,
                                      hDA2, db_pan2, sbb2,
                                      tmpS, labels, spec, mtf, acc);

    k_final<<<1, 1, 0, stream>>>(acc, out);
}